// Round 5
// baseline (279.041 us; speedup 1.0000x reference)
//
#include <hip/hip_runtime.h>
#include <hip/hip_bf16.h>
#include <cstdint>
#include <cstddef>

typedef unsigned int u32;
typedef __attribute__((ext_vector_type(8))) short s16x8;   // 8 bf16 (4 VGPR) MFMA A/B frag
typedef __attribute__((ext_vector_type(4))) short s16x4;   // 4 bf16, 8B pack
typedef __attribute__((ext_vector_type(4))) float f32x4;   // MFMA C/D frag
typedef __attribute__((ext_vector_type(2))) u32   u32x2;

#define MFMA(a,b,c) __builtin_amdgcn_mfma_f32_16x16x32_bf16(a,b,c,0,0,0)

#if __has_builtin(__builtin_amdgcn_mfma_f32_16x16x16bf16_1k)
#define MFMA16(a,b,c) __builtin_amdgcn_mfma_f32_16x16x16bf16_1k(a,b,c,0,0,0)
#else
static __device__ __forceinline__ f32x4 MFMA16(s16x4 a, s16x4 b, f32x4 c){
    f32x4 d;
    asm volatile("v_mfma_f32_16x16x16_bf16 %0, %1, %2, %3"
                 : "=v"(d) : "v"(a), "v"(b), "v"(c));
    return d;
}
#endif

__device__ __forceinline__ short f2bf(float f) {
    u32 u = __builtin_bit_cast(u32, f);
    u32 r = (u + 0x7fffu + ((u >> 16) & 1u)) >> 16;   // RNE
    return (short)r;
}
__device__ __forceinline__ float bf2f(short s) {
    return __builtin_bit_cast(float, ((u32)(unsigned short)s) << 16);
}
__device__ __forceinline__ u32 cvtpk(float lo, float hi) {
    u32 r;
    asm("v_cvt_pk_bf16_f32 %0, %1, %2" : "=v"(r) : "v"(lo), "v"(hi));
    return r;
}
__device__ __forceinline__ void async_copy16(void* lds, const void* g) {
    __builtin_amdgcn_global_load_lds((const __attribute__((address_space(1))) u32*)g,
                                     (__attribute__((address_space(3))) u32*)lds, 16, 0, 0);
}

// ---------------------------------------------------------------------------
// Prep: cast x (fp32 -> bf16), 8 elems/thread
// ---------------------------------------------------------------------------
__global__ __launch_bounds__(256) void cast_x(const float* __restrict__ x, short* __restrict__ xb) {
    int i = (blockIdx.x * 256 + threadIdx.x) * 8;
    float4 a = *(const float4*)&x[i];
    float4 b = *(const float4*)&x[i + 4];
    s16x8 v = { f2bf(a.x), f2bf(a.y), f2bf(a.z), f2bf(a.w),
                f2bf(b.x), f2bf(b.y), f2bf(b.z), f2bf(b.w) };
    *(s16x8*)&xb[i] = v;
}

// ---------------------------------------------------------------------------
// Prep: transpose + cast weights. seg 0..2 -> Wtqkv rows [seg*1024, +1024); seg 3 -> Wto.
// ---------------------------------------------------------------------------
__global__ __launch_bounds__(256)
void transpose_w(const float* __restrict__ wq, const float* __restrict__ wk,
                 const float* __restrict__ wv, const float* __restrict__ wo,
                 short* __restrict__ Wtqkv, short* __restrict__ Wto)
{
    __shared__ float sT[64][68];
    const int kt = blockIdx.x, nt = blockIdx.y, seg = blockIdx.z;
    const float* src = seg == 0 ? wq : seg == 1 ? wk : seg == 2 ? wv : wo;
    const int k0 = kt * 64, n0 = nt * 64;
    const int tid = threadIdx.x;
#pragma unroll
    for (int i = 0; i < 4; ++i) {
        int t2 = tid + i * 256;          // 0..1023 -> 64 rows x 16 float4
        int r = t2 >> 4, c4 = t2 & 15;
        *(float4*)&sT[r][c4 * 4] = *(const float4*)&src[(size_t)(k0 + r) * 1024 + n0 + c4 * 4];
    }
    __syncthreads();
#pragma unroll
    for (int i = 0; i < 2; ++i) {
        int t2 = tid + i * 256;
        int rn = t2 >> 3, ch = t2 & 7;
        s16x8 v;
#pragma unroll
        for (int j = 0; j < 8; ++j) v[j] = f2bf(sT[ch * 8 + j][rn]);
        if (seg < 3)
            *(s16x8*)&Wtqkv[(size_t)(seg * 1024 + n0 + rn) * 1024 + k0 + ch * 8] = v;
        else
            *(s16x8*)&Wto[(size_t)(n0 + rn) * 1024 + k0 + ch * 8] = v;
    }
}

// ---------------------------------------------------------------------------
// Prep: relkb [144][64] bf16 zero-padded rows>=129; relvT [64][128] bf16 (r<128).
// ---------------------------------------------------------------------------
__global__ __launch_bounds__(256)
void prep_tables(const float* __restrict__ relk, const float* __restrict__ relv,
                 short* __restrict__ relkb, short* __restrict__ relvT)
{
    int tid = threadIdx.x;
    for (int i = tid; i < 144 * 64; i += 256) {
        int r = i >> 6, d = i & 63;
        relkb[i] = (r < 129) ? f2bf(relk[r * 64 + d]) : (short)0;
    }
    for (int i = tid; i < 64 * 128; i += 256) {
        int d = i >> 7, r = i & 127;
        relvT[i] = f2bf(relv[r * 64 + d]);
    }
}

// ---------------------------------------------------------------------------
// Fused QKV GEMM; V segment stores TRANSPOSED ([bh][64 d][1024 l]) directly,
// eliminating the separate transpose_v kernel.
// ---------------------------------------------------------------------------
__global__ __launch_bounds__(256)
void gemm_qkv(const short* __restrict__ Ab, const short* __restrict__ Wt,
              const float* __restrict__ bq, const float* __restrict__ bk,
              const float* __restrict__ bv,
              short* __restrict__ Qb, short* __restrict__ Kb, short* __restrict__ Vtb)
{
    __shared__ __align__(16) short As[128 * 64];
    __shared__ __align__(16) short Bs[128 * 64];
    const int tid = threadIdx.x;
    const int w = tid >> 6, lane = tid & 63;
    const int lo16 = lane & 15, hi = lane >> 4;
    const int n0g = blockIdx.x * 128;
    const int m0 = blockIdx.y * 128;
    const int wr = w >> 1, wc = w & 1;

    f32x4 acc[4][4] = {};

    for (int t = 0; t < 16; ++t) {
        const int k0 = t * 64;
        __syncthreads();
#pragma unroll
        for (int i = 0; i < 4; ++i) {
            int o = i * 4096 + tid * 16;
            int row = o >> 7;
            int cb = o & 127;
            int sc = cb ^ ((row & 7) << 4);
            async_copy16((char*)As + o, Ab + (size_t)(m0 + row) * 1024 + k0 + (sc >> 1));
            async_copy16((char*)Bs + o, Wt + (size_t)(n0g + row) * 1024 + k0 + (sc >> 1));
        }
        __syncthreads();
#pragma unroll
        for (int ks = 0; ks < 2; ++ks) {
            s16x8 aF[4], bF[4];
#pragma unroll
            for (int mi = 0; mi < 4; ++mi) {
                int row = wr * 64 + mi * 16 + lo16;
                int cb = ks * 64 + hi * 16;
                aF[mi] = *(const s16x8*)((const char*)As + row * 128 + (cb ^ ((row & 7) << 4)));
            }
#pragma unroll
            for (int ni = 0; ni < 4; ++ni) {
                int row = wc * 64 + ni * 16 + lo16;
                int cb = ks * 64 + hi * 16;
                bF[ni] = *(const s16x8*)((const char*)Bs + row * 128 + (cb ^ ((row & 7) << 4)));
            }
#pragma unroll
            for (int mi = 0; mi < 4; ++mi)
#pragma unroll
                for (int ni = 0; ni < 4; ++ni)
                    acc[mi][ni] = MFMA(aF[mi], bF[ni], acc[mi][ni]);
        }
    }

    const int seg = n0g >> 10;
    const int nn = n0g & 1023;
    const float* bias = seg == 0 ? bq : seg == 1 ? bk : bv;
    float bv4[4];
#pragma unroll
    for (int ni = 0; ni < 4; ++ni) bv4[ni] = bias[nn + wc * 64 + ni * 16 + lo16];

    if (seg == 2) {
        // V: store transposed, 4 consecutive l per thread -> 8B stores
#pragma unroll
        for (int mi = 0; mi < 4; ++mi)
#pragma unroll
            for (int ni = 0; ni < 4; ++ni) {
                int nl = nn + wc * 64 + ni * 16 + lo16;
                int hh = nl >> 6, d = nl & 63;
                int mbase = m0 + wr * 64 + mi * 16 + hi * 4;
                int bb = mbase >> 10, l = mbase & 1023;
                s16x4 pk = { f2bf(acc[mi][ni][0] + bv4[ni]),
                             f2bf(acc[mi][ni][1] + bv4[ni]),
                             f2bf(acc[mi][ni][2] + bv4[ni]),
                             f2bf(acc[mi][ni][3] + bv4[ni]) };
                *(s16x4*)&Vtb[((size_t)(bb * 16 + hh) * 64 + d) * 1024 + l] = pk;
            }
    } else {
        short* out = seg == 0 ? Qb : Kb;
#pragma unroll
        for (int mi = 0; mi < 4; ++mi)
#pragma unroll
            for (int ni = 0; ni < 4; ++ni) {
                int nl = nn + wc * 64 + ni * 16 + lo16;
                int hh = nl >> 6, d = nl & 63;
#pragma unroll
                for (int r = 0; r < 4; ++r) {
                    int m = m0 + wr * 64 + mi * 16 + hi * 4 + r;
                    int bb = m >> 10, l = m & 1023;
                    out[(((size_t)bb * 16 + hh) * 1024 + l) * 64 + d] = f2bf(acc[mi][ni][r] + bv4[ni]);
                }
            }
    }
}

// ---------------------------------------------------------------------------
// Flash attention v3: PV via mfma_16x16x16 consuming the QK^T S-fragment
// DIRECTLY (no bpermute, no sP round-trip). Band fast-path; cvt_pk packing;
// K 2-block + V half-block register prefetch; setprio around MFMA clusters.
// Block = (bh, 64-query tile); 4 independent waves x 16 queries.
// ---------------------------------------------------------------------------
__device__ __forceinline__ void load_k(const short* Kbase, int k0, int lo16, int hi, s16x8* kr)
{
    const short* p0 = Kbase + (size_t)(k0 + lo16) * 64 + hi * 8;
    kr[0] = *(const s16x8*)p0;
    kr[1] = *(const s16x8*)(p0 + 32);
    const short* p1 = p0 + 16 * 64;
    kr[2] = *(const s16x8*)p1;
    kr[3] = *(const s16x8*)(p1 + 32);
}
// vr[f*4+df] = Vt[df*16+lo16][kf + f*16 + hi*4 .. +3]  (A-frag for 16x16x16)
__device__ __forceinline__ void load_v16(const short* Vtbase, int kf, int lo16, int hi, s16x4* vr)
{
#pragma unroll
    for (int f = 0; f < 2; ++f)
#pragma unroll
        for (int df = 0; df < 4; ++df)
            vr[f * 4 + df] = *(const s16x4*)(Vtbase + (size_t)(df * 16 + lo16) * 1024 + kf + f * 16 + hi * 4);
}

__device__ __forceinline__ void process32(
    int kf, int q0, int q_abs, int lo16, int hi,
    const s16x8* kr, const s16x4* vr,
    const s16x8& qB0, const s16x8& qB1,
    float qrel_lo, float qrel_hi,
    const short (*sQrelw)[148], short (*sBandw)[136], const short* sMaskP,
    f32x4* ctx, float& lsum, float& lov, float& hiv)
{
    f32x4 s0 = {0.f, 0.f, 0.f, 0.f}, s1 = {0.f, 0.f, 0.f, 0.f};
    __builtin_amdgcn_s_setprio(1);
    s0 = MFMA(kr[0], qB0, s0); s0 = MFMA(kr[1], qB1, s0);
    s1 = MFMA(kr[2], qB0, s1); s1 = MFMA(kr[3], qB1, s1);
    __builtin_amdgcn_s_setprio(0);

    // mask bias (broadcast within 16-lane group, 8B reads)
    s16x4 m0 = *(const s16x4*)&sMaskP[kf + hi * 4];
    s16x4 m1 = *(const s16x4*)&sMaskP[kf + 16 + hi * 4];

    float p[8];
    if (kf + 95 <= q0 || kf >= q0 + 79) {
        // whole block out of band: rel uniform 0 or 128
        const float qc = (kf < q0) ? qrel_lo : qrel_hi;
        float bs = 0.f;
#pragma unroll
        for (int r = 0; r < 4; ++r) {
            p[r]     = __expf(s0[r] + qc + bf2f(m0[r]));
            p[4 + r] = __expf(s1[r] + qc + bf2f(m1[r]));
        }
#pragma unroll
        for (int r = 0; r < 8; ++r) bs += p[r];
        lsum += bs;
        if (kf < q0) lov += bs; else hiv += bs;
    } else {
#pragma unroll
        for (int f = 0; f < 2; ++f)
#pragma unroll
            for (int r = 0; r < 4; ++r) {
                int k_abs = kf + f * 16 + hi * 4 + r;
                int dd = k_abs - q_abs;
                dd = dd < -64 ? -64 : (dd > 64 ? 64 : dd);
                int rel = dd + 64;
                float sv = f ? s1[r] : s0[r];
                float mv = bf2f(f ? m1[r] : m0[r]);
                float pex = __expf(sv + bf2f(sQrelw[lo16][rel]) + mv);
                p[f * 4 + r] = pex;
                lsum += pex;
                if (rel >= 1 && rel <= 127) sBandw[lo16][rel] = f2bf(pex);
                else if (rel == 0) lov += pex;
                else hiv += pex;
            }
    }

    // S-frag (col=q=lo16, k=hi*4+r) IS the 16x16x16 B-operand layout: no shuffle.
    u32x2 w0 = { cvtpk(p[0], p[1]), cvtpk(p[2], p[3]) };
    u32x2 w1 = { cvtpk(p[4], p[5]), cvtpk(p[6], p[7]) };
    s16x4 pf0 = __builtin_bit_cast(s16x4, w0);
    s16x4 pf1 = __builtin_bit_cast(s16x4, w1);
    __builtin_amdgcn_s_setprio(1);
#pragma unroll
    for (int df = 0; df < 4; ++df) ctx[df] = MFMA16(vr[df], pf0, ctx[df]);
#pragma unroll
    for (int df = 0; df < 4; ++df) ctx[df] = MFMA16(vr[4 + df], pf1, ctx[df]);
    __builtin_amdgcn_s_setprio(0);
}

__global__ __launch_bounds__(256, 4)
void attn_mfma(const short* __restrict__ Qb, const short* __restrict__ Kb,
               const short* __restrict__ Vtb, const short* __restrict__ relkb,
               const short* __restrict__ relvTb, const float* __restrict__ relv_f32,
               const float* __restrict__ mask, short* __restrict__ CTXb)
{
    __shared__ __align__(16) short sMaskP[1024];       // bf16 mask * -1e9
    __shared__ __align__(16) short sQrel[4][16][148];  // bf16 Qrel[q][r], r<=143
    __shared__ __align__(16) short sBand[4][16][136];  // bf16 band weights r in 1..127

    const int tid = threadIdx.x;
    const int w = tid >> 6, lane = tid & 63;
    const int lo16 = lane & 15, hi = lane >> 4;

    // XCD-aware swizzle (1024 = 8*128, bijective)
    const int p = blockIdx.x;
    const int bid = (p & 7) * 128 + (p >> 3);
    const int bh = bid >> 4;
    const int qt = bid & 15;
    const int b = bh >> 4, h = bh & 15;
    const int q0 = qt * 64 + w * 16;
    const int q_abs = q0 + lo16;

    const short* Kbase = Kb + (size_t)bh * 65536;
    const short* Vtbase = Vtb + (size_t)bh * 65536;

    // persistent Q fragments (B-operand: col = q = lane&15, depth = hi*8+j)
    const short* qptr = Qb + ((size_t)bh * 1024 + q_abs) * 64 + hi * 8;
    const s16x8 qB0 = *(const s16x8*)qptr;
    const s16x8 qB1 = *(const s16x8*)(qptr + 32);

    // init shared: maskP (block-wide), sBand zero (per-wave region)
    {
        float4 mv = *(const float4*)&mask[b * 1024 + tid * 4];
        s16x4 mp = { f2bf(mv.x * -1e9f), f2bf(mv.y * -1e9f),
                     f2bf(mv.z * -1e9f), f2bf(mv.w * -1e9f) };
        *(s16x4*)&sMaskP[tid * 4] = mp;
    }
    {
        u32* bz = (u32*)&sBand[w][0][0];   // 16*136 shorts = 1088 u32 per wave
#pragma unroll
        for (int i = 0; i < 17; ++i) bz[lane + i * 64] = 0u;
    }

    // Qrel^T = relk @ Q^T : 9 r-frags -> sQrel[w][q][r] (bf16)
#pragma unroll
    for (int rf = 0; rf < 9; ++rf) {
        const short* rp = relkb + (size_t)(rf * 16 + lo16) * 64 + hi * 8;
        s16x8 rA0 = *(const s16x8*)rp;
        s16x8 rA1 = *(const s16x8*)(rp + 32);
        f32x4 dq = {0.f, 0.f, 0.f, 0.f};
        dq = MFMA(rA0, qB0, dq);
        dq = MFMA(rA1, qB1, dq);
        s16x4 pk = { f2bf(dq[0]), f2bf(dq[1]), f2bf(dq[2]), f2bf(dq[3]) };
        *(s16x4*)&sQrel[w][lo16][rf * 16 + hi * 4] = pk;
    }
    __syncthreads();   // sMaskP is cross-wave; also fences sQrel writes

    const float qrel_lo = bf2f(sQrel[w][lo16][0]);
    const float qrel_hi = bf2f(sQrel[w][lo16][128]);

    f32x4 ctx[4] = {};
    float lsum = 0.f, lov = 0.f, hiv = 0.f;

    // K prefetched 2 half-blocks ahead, V one half-block ahead
    s16x8 ka[4], kb_[4];
    s16x4 vA[8], vB[8];
    load_k(Kbase, 0, lo16, hi, ka);
    load_k(Kbase, 32, lo16, hi, kb_);
    load_v16(Vtbase, 0, lo16, hi, vA);

    for (int k0 = 0; k0 < 1024; k0 += 64) {
        load_v16(Vtbase, k0 + 32, lo16, hi, vB);
        process32(k0, q0, q_abs, lo16, hi, ka, vA, qB0, qB1, qrel_lo, qrel_hi,
                  sQrel[w], sBand[w], sMaskP, ctx, lsum, lov, hiv);
        load_k(Kbase, (k0 + 64) & 1023, lo16, hi, ka);
        load_v16(Vtbase, (k0 + 64) & 1023, lo16, hi, vA);
        process32(k0 + 32, q0, q_abs, lo16, hi, kb_, vB, qB0, qB1, qrel_lo, qrel_hi,
                  sQrel[w], sBand[w], sMaskP, ctx, lsum, lov, hiv);
        load_k(Kbase, (k0 + 96) & 1023, lo16, hi, kb_);
    }

    // band rel_v contribution: ctx^T += relvT-frag x sBand-frag (unnormalized)
#pragma unroll
    for (int ks = 0; ks < 4; ++ks) {
        s16x8 bB = *(const s16x8*)&sBand[w][lo16][ks * 32 + hi * 8];
#pragma unroll
        for (int df = 0; df < 4; ++df) {
            s16x8 rA = *(const s16x8*)(relvTb + (size_t)(df * 16 + lo16) * 128 + ks * 32 + hi * 8);
            ctx[df] = MFMA(rA, bB, ctx[df]);
        }
    }

    // reduce per-q stats across the 4 hi-groups
    lsum += __shfl_xor(lsum, 16); lsum += __shfl_xor(lsum, 32);
    lov  += __shfl_xor(lov, 16);  lov  += __shfl_xor(lov, 32);
    hiv  += __shfl_xor(hiv, 16);  hiv  += __shfl_xor(hiv, 32);
    const float inv = 1.0f / lsum;

    // tails (clipped buckets 0 / 128) + normalize + store bf16 ctx
#pragma unroll
    for (int df = 0; df < 4; ++df) {
        s16x4 pk;
#pragma unroll
        for (int r = 0; r < 4; ++r) {
            int d = df * 16 + hi * 4 + r;
            float t = ctx[df][r] + lov * relv_f32[d] + hiv * relv_f32[128 * 64 + d];
            pk[r] = f2bf(t * inv);
        }
        *(s16x4*)(CTXb + ((size_t)(b * 1024) + q_abs) * 1024 + h * 64 + df * 16 + hi * 4) = pk;
    }
}

// ---------------------------------------------------------------------------
// Output GEMM: out[4096,1024] = CTXb @ wo + bo (fp32 out). 128x64 tile, BK=64.
// ---------------------------------------------------------------------------
__global__ __launch_bounds__(256)
void gemm_out(const short* __restrict__ Ab, const short* __restrict__ Wto,
              const float* __restrict__ bo, float* __restrict__ out)
{
    __shared__ __align__(16) short As[128 * 64];
    __shared__ __align__(16) short Bs[64 * 64];
    const int tid = threadIdx.x;
    const int w = tid >> 6, lane = tid & 63;
    const int lo16 = lane & 15, hi = lane >> 4;
    const int n0 = blockIdx.x * 64;
    const int m0 = blockIdx.y * 128;
    const int wr = w;

    f32x4 acc[2][4] = {};

    for (int t = 0; t < 16; ++t) {
        const int k0 = t * 64;
        __syncthreads();
#pragma unroll
        for (int i = 0; i < 4; ++i) {
            int o = i * 4096 + tid * 16;
            int row = o >> 7;
            int cb = o & 127;
            int sc = cb ^ ((row & 7) << 4);
            async_copy16((char*)As + o, Ab + (size_t)(m0 + row) * 1024 + k0 + (sc >> 1));
        }
#pragma unroll
        for (int i = 0; i < 2; ++i) {
            int o = i * 4096 + tid * 16;
            int row = o >> 7;
            int cb = o & 127;
            int sc = cb ^ ((row & 7) << 4);
            async_copy16((char*)Bs + o, Wto + (size_t)(n0 + row) * 1024 + k0 + (sc >> 1));
        }
        __syncthreads();
#pragma unroll
        for (int ks = 0; ks < 2; ++ks) {
            s16x8 aF[2], bF[4];
#pragma unroll
            for (int mi = 0; mi < 2; ++mi) {
                int row = wr * 32 + mi * 16 + lo16;
                int cb = ks * 64 + hi * 16;
                aF[mi] = *(const s16x8*)((const char*)As + row * 128 + (cb ^ ((row & 7) << 4)));
            }
#pragma unroll
            for (int ni = 0; ni < 4; ++ni) {
                int row = ni * 16 + lo16;
                int cb = ks * 64 + hi * 16;
                bF[ni] = *(const s16x8*)((const char*)Bs + row * 128 + (cb ^ ((row & 7) << 4)));
            }
#pragma unroll
            for (int mi = 0; mi < 2; ++mi)
#pragma unroll
                for (int ni = 0; ni < 4; ++ni)
                    acc[mi][ni] = MFMA(aF[mi], bF[ni], acc[mi][ni]);
        }
    }

    float bv4[4];
#pragma unroll
    for (int ni = 0; ni < 4; ++ni) bv4[ni] = bo[n0 + ni * 16 + lo16];
#pragma unroll
    for (int mi = 0; mi < 2; ++mi)
#pragma unroll
        for (int ni = 0; ni < 4; ++ni)
#pragma unroll
            for (int r = 0; r < 4; ++r) {
                int m = m0 + wr * 32 + mi * 16 + hi * 4 + r;
                out[(size_t)m * 1024 + n0 + ni * 16 + lo16] = acc[mi][ni][r] + bv4[ni];
            }
}

// ---------------------------------------------------------------------------
extern "C" void kernel_launch(void* const* d_in, const int* in_sizes, int n_in,
                              void* d_out, int out_size, void* d_ws, size_t ws_size,
                              hipStream_t stream)
{
    (void)in_sizes; (void)n_in; (void)out_size; (void)ws_size;
    const float* x    = (const float*)d_in[0];
    const float* mask = (const float*)d_in[1];
    const float* wq   = (const float*)d_in[2];
    const float* bq   = (const float*)d_in[3];
    const float* wk   = (const float*)d_in[4];
    const float* bk   = (const float*)d_in[5];
    const float* wv   = (const float*)d_in[6];
    const float* bv   = (const float*)d_in[7];
    const float* wo   = (const float*)d_in[8];
    const float* bo   = (const float*)d_in[9];
    const float* relk = (const float*)d_in[10];
    const float* relv = (const float*)d_in[11];
    float* out = (float*)d_out;

    char* p = (char*)d_ws;
    short* xb    = (short*)p; p += (size_t)4096 * 1024 * 2;     // 8 MB
    short* Wtqkv = (short*)p; p += (size_t)3072 * 1024 * 2;     // 6 MB
    short* Wto   = (short*)p; p += (size_t)1024 * 1024 * 2;     // 2 MB
    short* Qb    = (short*)p; p += (size_t)4096 * 1024 * 2;     // 8 MB
    short* Kb    = (short*)p; p += (size_t)4096 * 1024 * 2;     // 8 MB
    short* Vtb   = (short*)p; p += (size_t)4096 * 1024 * 2;     // 8 MB
    short* CTXb  = (short*)p; p += (size_t)4096 * 1024 * 2;     // 8 MB
    short* relkb = (short*)p; p += (size_t)144 * 64 * 2;
    short* relvT = (short*)p; p += (size_t)64 * 128 * 2;

    cast_x       <<<2048, 256, 0, stream>>>(x, xb);
    transpose_w  <<<dim3(16, 16, 4), 256, 0, stream>>>(wq, wk, wv, wo, Wtqkv, Wto);
    prep_tables  <<<1, 256, 0, stream>>>(relk, relv, relkb, relvT);
    gemm_qkv     <<<dim3(24, 32), 256, 0, stream>>>(xb, Wtqkv, bq, bk, bv, Qb, Kb, Vtb);
    attn_mfma    <<<1024, 256, 0, stream>>>(Qb, Kb, Vtb, relkb, relvT, relv, mask, CTXb);
    gemm_out     <<<dim3(16, 32), 256, 0, stream>>>(CTXb, Wto, bo, out);
}

// Round 6
// 175.080 us; speedup vs baseline: 1.5938x; 1.5938x over previous
//
#include <hip/hip_runtime.h>
#include <hip/hip_bf16.h>
#include <cstdint>
#include <cstddef>

typedef unsigned int u32;
typedef __attribute__((ext_vector_type(8))) short s16x8;   // 8 bf16 (4 VGPR) MFMA A/B frag
typedef __attribute__((ext_vector_type(4))) short s16x4;   // 4 bf16, 8B pack
typedef __attribute__((ext_vector_type(4))) float f32x4;   // MFMA C/D frag
typedef __attribute__((ext_vector_type(2))) u32   u32x2;

#define MFMA(a,b,c) __builtin_amdgcn_mfma_f32_16x16x32_bf16(a,b,c,0,0,0)

#if __has_builtin(__builtin_amdgcn_mfma_f32_16x16x16bf16_1k)
#define MFMA16(a,b,c) __builtin_amdgcn_mfma_f32_16x16x16bf16_1k(a,b,c,0,0,0)
#else
static __device__ __forceinline__ f32x4 MFMA16(s16x4 a, s16x4 b, f32x4 c){
    f32x4 d;
    asm("v_mfma_f32_16x16x16_bf16 %0, %1, %2, %3"
        : "=v"(d) : "v"(a), "v"(b), "v"(c));
    return d;
}
#endif

__device__ __forceinline__ short f2bf(float f) {
    u32 u = __builtin_bit_cast(u32, f);
    u32 r = (u + 0x7fffu + ((u >> 16) & 1u)) >> 16;   // RNE
    return (short)r;
}
__device__ __forceinline__ float bf2f(short s) {
    return __builtin_bit_cast(float, ((u32)(unsigned short)s) << 16);
}
__device__ __forceinline__ u32 cvtpk(float lo, float hi) {
    u32 r;
    asm("v_cvt_pk_bf16_f32 %0, %1, %2" : "=v"(r) : "v"(lo), "v"(hi));
    return r;
}
__device__ __forceinline__ void async_copy16(void* lds, const void* g) {
    __builtin_amdgcn_global_load_lds((const __attribute__((address_space(1))) u32*)g,
                                     (__attribute__((address_space(3))) u32*)lds, 16, 0, 0);
}

// ---------------------------------------------------------------------------
// Prep: cast x (fp32 -> bf16), 8 elems/thread
// ---------------------------------------------------------------------------
__global__ __launch_bounds__(256) void cast_x(const float* __restrict__ x, short* __restrict__ xb) {
    int i = (blockIdx.x * 256 + threadIdx.x) * 8;
    float4 a = *(const float4*)&x[i];
    float4 b = *(const float4*)&x[i + 4];
    s16x8 v = { f2bf(a.x), f2bf(a.y), f2bf(a.z), f2bf(a.w),
                f2bf(b.x), f2bf(b.y), f2bf(b.z), f2bf(b.w) };
    *(s16x8*)&xb[i] = v;
}

// ---------------------------------------------------------------------------
// Prep: transpose + cast weights. seg 0..2 -> Wtqkv rows [seg*1024, +1024); seg 3 -> Wto.
// ---------------------------------------------------------------------------
__global__ __launch_bounds__(256)
void transpose_w(const float* __restrict__ wq, const float* __restrict__ wk,
                 const float* __restrict__ wv, const float* __restrict__ wo,
                 short* __restrict__ Wtqkv, short* __restrict__ Wto)
{
    __shared__ float sT[64][68];
    const int kt = blockIdx.x, nt = blockIdx.y, seg = blockIdx.z;
    const float* src = seg == 0 ? wq : seg == 1 ? wk : seg == 2 ? wv : wo;
    const int k0 = kt * 64, n0 = nt * 64;
    const int tid = threadIdx.x;
#pragma unroll
    for (int i = 0; i < 4; ++i) {
        int t2 = tid + i * 256;          // 0..1023 -> 64 rows x 16 float4
        int r = t2 >> 4, c4 = t2 & 15;
        *(float4*)&sT[r][c4 * 4] = *(const float4*)&src[(size_t)(k0 + r) * 1024 + n0 + c4 * 4];
    }
    __syncthreads();
#pragma unroll
    for (int i = 0; i < 2; ++i) {
        int t2 = tid + i * 256;
        int rn = t2 >> 3, ch = t2 & 7;
        s16x8 v;
#pragma unroll
        for (int j = 0; j < 8; ++j) v[j] = f2bf(sT[ch * 8 + j][rn]);
        if (seg < 3)
            *(s16x8*)&Wtqkv[(size_t)(seg * 1024 + n0 + rn) * 1024 + k0 + ch * 8] = v;
        else
            *(s16x8*)&Wto[(size_t)(n0 + rn) * 1024 + k0 + ch * 8] = v;
    }
}

// ---------------------------------------------------------------------------
// Prep: relkb [144][64] bf16 zero-padded rows>=129; relvT [64][128] bf16 (r<128).
// ---------------------------------------------------------------------------
__global__ __launch_bounds__(256)
void prep_tables(const float* __restrict__ relk, const float* __restrict__ relv,
                 short* __restrict__ relkb, short* __restrict__ relvT)
{
    int tid = threadIdx.x;
    for (int i = tid; i < 144 * 64; i += 256) {
        int r = i >> 6, d = i & 63;
        relkb[i] = (r < 129) ? f2bf(relk[r * 64 + d]) : (short)0;
    }
    for (int i = tid; i < 64 * 128; i += 256) {
        int d = i >> 7, r = i & 127;
        relvT[i] = f2bf(relv[r * 64 + d]);
    }
}

// ---------------------------------------------------------------------------
// Fused QKV GEMM; V segment stores TRANSPOSED ([bh][64 d][1024 l]) directly.
// ---------------------------------------------------------------------------
__global__ __launch_bounds__(256)
void gemm_qkv(const short* __restrict__ Ab, const short* __restrict__ Wt,
              const float* __restrict__ bq, const float* __restrict__ bk,
              const float* __restrict__ bv,
              short* __restrict__ Qb, short* __restrict__ Kb, short* __restrict__ Vtb)
{
    __shared__ __align__(16) short As[128 * 64];
    __shared__ __align__(16) short Bs[128 * 64];
    const int tid = threadIdx.x;
    const int w = tid >> 6, lane = tid & 63;
    const int lo16 = lane & 15, hi = lane >> 4;
    const int n0g = blockIdx.x * 128;
    const int m0 = blockIdx.y * 128;
    const int wr = w >> 1, wc = w & 1;

    f32x4 acc[4][4] = {};

    for (int t = 0; t < 16; ++t) {
        const int k0 = t * 64;
        __syncthreads();
#pragma unroll
        for (int i = 0; i < 4; ++i) {
            int o = i * 4096 + tid * 16;
            int row = o >> 7;
            int cb = o & 127;
            int sc = cb ^ ((row & 7) << 4);
            async_copy16((char*)As + o, Ab + (size_t)(m0 + row) * 1024 + k0 + (sc >> 1));
            async_copy16((char*)Bs + o, Wt + (size_t)(n0g + row) * 1024 + k0 + (sc >> 1));
        }
        __syncthreads();
#pragma unroll
        for (int ks = 0; ks < 2; ++ks) {
            s16x8 aF[4], bF[4];
#pragma unroll
            for (int mi = 0; mi < 4; ++mi) {
                int row = wr * 64 + mi * 16 + lo16;
                int cb = ks * 64 + hi * 16;
                aF[mi] = *(const s16x8*)((const char*)As + row * 128 + (cb ^ ((row & 7) << 4)));
            }
#pragma unroll
            for (int ni = 0; ni < 4; ++ni) {
                int row = wc * 64 + ni * 16 + lo16;
                int cb = ks * 64 + hi * 16;
                bF[ni] = *(const s16x8*)((const char*)Bs + row * 128 + (cb ^ ((row & 7) << 4)));
            }
#pragma unroll
            for (int mi = 0; mi < 4; ++mi)
#pragma unroll
                for (int ni = 0; ni < 4; ++ni)
                    acc[mi][ni] = MFMA(aF[mi], bF[ni], acc[mi][ni]);
        }
    }

    const int seg = n0g >> 10;
    const int nn = n0g & 1023;
    const float* bias = seg == 0 ? bq : seg == 1 ? bk : bv;
    float bv4[4];
#pragma unroll
    for (int ni = 0; ni < 4; ++ni) bv4[ni] = bias[nn + wc * 64 + ni * 16 + lo16];

    if (seg == 2) {
        // V: store transposed, 4 consecutive l per thread -> 8B stores
#pragma unroll
        for (int mi = 0; mi < 4; ++mi)
#pragma unroll
            for (int ni = 0; ni < 4; ++ni) {
                int nl = nn + wc * 64 + ni * 16 + lo16;
                int hh = nl >> 6, d = nl & 63;
                int mbase = m0 + wr * 64 + mi * 16 + hi * 4;
                int bb = mbase >> 10, l = mbase & 1023;
                s16x4 pk = { f2bf(acc[mi][ni][0] + bv4[ni]),
                             f2bf(acc[mi][ni][1] + bv4[ni]),
                             f2bf(acc[mi][ni][2] + bv4[ni]),
                             f2bf(acc[mi][ni][3] + bv4[ni]) };
                *(s16x4*)&Vtb[((size_t)(bb * 16 + hh) * 64 + d) * 1024 + l] = pk;
            }
    } else {
        short* out = seg == 0 ? Qb : Kb;
#pragma unroll
        for (int mi = 0; mi < 4; ++mi)
#pragma unroll
            for (int ni = 0; ni < 4; ++ni) {
                int nl = nn + wc * 64 + ni * 16 + lo16;
                int hh = nl >> 6, d = nl & 63;
#pragma unroll
                for (int r = 0; r < 4; ++r) {
                    int m = m0 + wr * 64 + mi * 16 + hi * 4 + r;
                    int bb = m >> 10, l = m & 1023;
                    out[(((size_t)bb * 16 + hh) * 1024 + l) * 64 + d] = f2bf(acc[mi][ni][r] + bv4[ni]);
                }
            }
    }
}

// ---------------------------------------------------------------------------
// Flash attention v4: K/V staged in LDS per BLOCK (shared by 4 waves, 4x less
// L2 traffic), double-buffered 32-k tiles via global_load_lds + 1 barrier/tile.
// K: 16B-chunk XOR swizzle (pre-swizzled source) -> clean b128 reads.
// V [d][k]: same chunk swizzle -> b64 reads <=4-way.
// PV via mfma_16x16x16 consuming the S-fragment directly. Band fast-path.
// ---------------------------------------------------------------------------
__device__ __forceinline__ void process32(
    int kf, int q0, int q_abs, int lo16, int hi,
    const short* __restrict__ sKc, const short* __restrict__ sVc,
    const s16x8& qB0, const s16x8& qB1,
    float qrel_lo, float qrel_hi,
    const short (*sQrelw)[148], short (*sBandw)[128], const short* sMaskP,
    f32x4* ctx, float& lsum, float& lov, float& hiv)
{
    const int km = lo16 & 7;
    const s16x8 kr0 = *(const s16x8*)(sKc + lo16 * 64 + ((hi ^ km) << 3));
    const s16x8 kr1 = *(const s16x8*)(sKc + lo16 * 64 + (((hi + 4) ^ km) << 3));
    const s16x8 kr2 = *(const s16x8*)(sKc + (lo16 + 16) * 64 + ((hi ^ km) << 3));
    const s16x8 kr3 = *(const s16x8*)(sKc + (lo16 + 16) * 64 + (((hi + 4) ^ km) << 3));

    f32x4 s0 = {0.f, 0.f, 0.f, 0.f}, s1 = {0.f, 0.f, 0.f, 0.f};
    __builtin_amdgcn_s_setprio(1);
    s0 = MFMA(kr0, qB0, s0); s0 = MFMA(kr1, qB1, s0);
    s1 = MFMA(kr2, qB0, s1); s1 = MFMA(kr3, qB1, s1);
    __builtin_amdgcn_s_setprio(0);

    // V fragments (issued early; lgkm waits handled by compiler)
    const int vm = (lo16 & 3) << 1;
    s16x4 vr[8];
#pragma unroll
    for (int f = 0; f < 2; ++f)
#pragma unroll
        for (int df = 0; df < 4; ++df) {
            int d = df * 16 + lo16;
            vr[f * 4 + df] = *(const s16x4*)(sVc + d * 32 + (((f * 4 + hi) ^ vm) << 2));
        }

    // mask bias (broadcast within 16-lane group, 8B reads)
    s16x4 m0 = *(const s16x4*)&sMaskP[kf + hi * 4];
    s16x4 m1 = *(const s16x4*)&sMaskP[kf + 16 + hi * 4];

    float p[8];
    if (kf + 95 <= q0 || kf >= q0 + 79) {
        // whole block out of band: rel uniform 0 or 128
        const float qc = (kf < q0) ? qrel_lo : qrel_hi;
        float bs = 0.f;
#pragma unroll
        for (int r = 0; r < 4; ++r) {
            p[r]     = __expf(s0[r] + qc + bf2f(m0[r]));
            p[4 + r] = __expf(s1[r] + qc + bf2f(m1[r]));
        }
#pragma unroll
        for (int r = 0; r < 8; ++r) bs += p[r];
        lsum += bs;
        if (kf < q0) lov += bs; else hiv += bs;
    } else {
#pragma unroll
        for (int f = 0; f < 2; ++f)
#pragma unroll
            for (int r = 0; r < 4; ++r) {
                int k_abs = kf + f * 16 + hi * 4 + r;
                int dd = k_abs - q_abs;
                dd = dd < -64 ? -64 : (dd > 64 ? 64 : dd);
                int rel = dd + 64;
                float sv = f ? s1[r] : s0[r];
                float mv = bf2f(f ? m1[r] : m0[r]);
                float pex = __expf(sv + bf2f(sQrelw[lo16][rel]) + mv);
                p[f * 4 + r] = pex;
                lsum += pex;
                if (rel >= 1 && rel <= 127) sBandw[lo16][rel] = f2bf(pex);
                else if (rel == 0) lov += pex;
                else hiv += pex;
            }
    }

    // S-frag (col=q=lo16, k=hi*4+r) IS the 16x16x16 B-operand layout: no shuffle.
    u32x2 w0 = { cvtpk(p[0], p[1]), cvtpk(p[2], p[3]) };
    u32x2 w1 = { cvtpk(p[4], p[5]), cvtpk(p[6], p[7]) };
    s16x4 pf0 = __builtin_bit_cast(s16x4, w0);
    s16x4 pf1 = __builtin_bit_cast(s16x4, w1);
    __builtin_amdgcn_s_setprio(1);
#pragma unroll
    for (int df = 0; df < 4; ++df) ctx[df] = MFMA16(vr[df], pf0, ctx[df]);
#pragma unroll
    for (int df = 0; df < 4; ++df) ctx[df] = MFMA16(vr[4 + df], pf1, ctx[df]);
    __builtin_amdgcn_s_setprio(0);
}

__global__ __launch_bounds__(256, 3)
void attn_mfma(const short* __restrict__ Qb, const short* __restrict__ Kb,
               const short* __restrict__ Vtb, const short* __restrict__ relkb,
               const short* __restrict__ relvTb, const float* __restrict__ relv_f32,
               const float* __restrict__ mask, short* __restrict__ CTXb)
{
    __shared__ __align__(16) short sK[2][32 * 64];     // 4KB/buf, swizzled rows k
    __shared__ __align__(16) short sV[2][64 * 32];     // 4KB/buf, swizzled rows d
    __shared__ __align__(16) short sMaskP[1024];       // bf16 mask * -1e9
    __shared__ __align__(16) short sQrel[4][16][148];  // bf16 Qrel[q][r], r<=143
    __shared__ __align__(16) short sBand[4][16][128];  // bf16 band weights r in 1..127

    const int tid = threadIdx.x;
    const int w = tid >> 6, lane = tid & 63;
    const int lo16 = lane & 15, hi = lane >> 4;

    // XCD-aware swizzle (1024 = 8*128, bijective); same-bh blocks share an XCD L2
    const int p = blockIdx.x;
    const int bid = (p & 7) * 128 + (p >> 3);
    const int bh = bid >> 4;
    const int qt = bid & 15;
    const int b = bh >> 4, h = bh & 15;
    const int q0 = qt * 64 + w * 16;
    const int q_abs = q0 + lo16;

    const short* Kbase = Kb + (size_t)bh * 65536;
    const short* Vtbase = Vtb + (size_t)bh * 65536;

    // staging geometry (per thread, 1x16B for K + 1x16B for V per tile)
    const int skr = tid >> 3, skc = tid & 7;             // K: row 0..31, chunk 0..7
    const int svd = tid >> 2, svc = tid & 3;             // V: row d 0..63, chunk 0..3
    const short* ksrc = Kbase + (size_t)skr * 64 + ((skc ^ (skr & 7)) << 3);
    const short* vsrc = Vtbase + (size_t)svd * 1024 + ((svc ^ (svd & 3)) << 3);

    // stage tile 0
    async_copy16((char*)&sK[0][0] + tid * 16, ksrc);
    async_copy16((char*)&sV[0][0] + tid * 16, vsrc);

    // persistent Q fragments (B-operand: col = q = lane&15, depth = hi*8+j)
    const short* qptr = Qb + ((size_t)bh * 1024 + q_abs) * 64 + hi * 8;
    const s16x8 qB0 = *(const s16x8*)qptr;
    const s16x8 qB1 = *(const s16x8*)(qptr + 32);

    // init shared: maskP (block-wide), sBand zero (per-wave region)
    {
        float4 mv = *(const float4*)&mask[b * 1024 + tid * 4];
        s16x4 mp = { f2bf(mv.x * -1e9f), f2bf(mv.y * -1e9f),
                     f2bf(mv.z * -1e9f), f2bf(mv.w * -1e9f) };
        *(s16x4*)&sMaskP[tid * 4] = mp;
    }
    {
        u32* bz = (u32*)&sBand[w][0][0];   // 16*128 shorts = 1024 u32 per wave
#pragma unroll
        for (int i = 0; i < 16; ++i) bz[lane + i * 64] = 0u;
    }

    // Qrel^T = relk @ Q^T : 9 r-frags -> sQrel[w][q][r] (bf16)
#pragma unroll
    for (int rf = 0; rf < 9; ++rf) {
        const short* rp = relkb + (size_t)(rf * 16 + lo16) * 64 + hi * 8;
        s16x8 rA0 = *(const s16x8*)rp;
        s16x8 rA1 = *(const s16x8*)(rp + 32);
        f32x4 dq = {0.f, 0.f, 0.f, 0.f};
        dq = MFMA(rA0, qB0, dq);
        dq = MFMA(rA1, qB1, dq);
        s16x4 pk = { f2bf(dq[0]), f2bf(dq[1]), f2bf(dq[2]), f2bf(dq[3]) };
        *(s16x4*)&sQrel[w][lo16][rf * 16 + hi * 4] = pk;
    }
    __syncthreads();   // drains stage(0) vmcnt; fences sMaskP/sQrel

    const float qrel_lo = bf2f(sQrel[w][lo16][0]);
    const float qrel_hi = bf2f(sQrel[w][lo16][128]);

    f32x4 ctx[4] = {};
    float lsum = 0.f, lov = 0.f, hiv = 0.f;

    for (int t = 0; t < 32; ++t) {
        if (t < 31) {   // stage next tile into the other buffer
            int kfn = (t + 1) * 32;
            async_copy16((char*)&sK[(t + 1) & 1][0] + tid * 16, ksrc + (size_t)kfn * 64);
            async_copy16((char*)&sV[(t + 1) & 1][0] + tid * 16, vsrc + kfn);
        }
        process32(t * 32, q0, q_abs, lo16, hi, sK[t & 1], sV[t & 1],
                  qB0, qB1, qrel_lo, qrel_hi,
                  sQrel[w], sBand[w], sMaskP, ctx, lsum, lov, hiv);
        __syncthreads();   // drains staging vmcnt + protects buffer reuse
    }

    // band rel_v contribution: ctx^T += relvT-frag x sBand-frag (unnormalized)
#pragma unroll
    for (int ks = 0; ks < 4; ++ks) {
        s16x8 bB = *(const s16x8*)&sBand[w][lo16][ks * 32 + hi * 8];
#pragma unroll
        for (int df = 0; df < 4; ++df) {
            s16x8 rA = *(const s16x8*)(relvTb + (size_t)(df * 16 + lo16) * 128 + ks * 32 + hi * 8);
            ctx[df] = MFMA(rA, bB, ctx[df]);
        }
    }

    // reduce per-q stats across the 4 hi-groups
    lsum += __shfl_xor(lsum, 16); lsum += __shfl_xor(lsum, 32);
    lov  += __shfl_xor(lov, 16);  lov  += __shfl_xor(lov, 32);
    hiv  += __shfl_xor(hiv, 16);  hiv  += __shfl_xor(hiv, 32);
    const float inv = 1.0f / lsum;

    // tails (clipped buckets 0 / 128) + normalize + store bf16 ctx
#pragma unroll
    for (int df = 0; df < 4; ++df) {
        s16x4 pk;
#pragma unroll
        for (int r = 0; r < 4; ++r) {
            int d = df * 16 + hi * 4 + r;
            float t = ctx[df][r] + lov * relv_f32[d] + hiv * relv_f32[128 * 64 + d];
            pk[r] = f2bf(t * inv);
        }
        *(s16x4*)(CTXb + ((size_t)(b * 1024) + q_abs) * 1024 + h * 64 + df * 16 + hi * 4) = pk;
    }
}

// ---------------------------------------------------------------------------
// Output GEMM: out[4096,1024] = CTXb @ wo + bo (fp32 out). 128x64 tile, BK=64.
// ---------------------------------------------------------------------------
__global__ __launch_bounds__(256)
void gemm_out(const short* __restrict__ Ab, const short* __restrict__ Wto,
              const float* __restrict__ bo, float* __restrict__ out)
{
    __shared__ __align__(16) short As[128 * 64];
    __shared__ __align__(16) short Bs[64 * 64];
    const int tid = threadIdx.x;
    const int w = tid >> 6, lane = tid & 63;
    const int lo16 = lane & 15, hi = lane >> 4;
    const int n0 = blockIdx.x * 64;
    const int m0 = blockIdx.y * 128;
    const int wr = w;

    f32x4 acc[2][4] = {};

    for (int t = 0; t < 16; ++t) {
        const int k0 = t * 64;
        __syncthreads();
#pragma unroll
        for (int i = 0; i < 4; ++i) {
            int o = i * 4096 + tid * 16;
            int row = o >> 7;
            int cb = o & 127;
            int sc = cb ^ ((row & 7) << 4);
            async_copy16((char*)As + o, Ab + (size_t)(m0 + row) * 1024 + k0 + (sc >> 1));
        }
#pragma unroll
        for (int i = 0; i < 2; ++i) {
            int o = i * 4096 + tid * 16;
            int row = o >> 7;
            int cb = o & 127;
            int sc = cb ^ ((row & 7) << 4);
            async_copy16((char*)Bs + o, Wto + (size_t)(n0 + row) * 1024 + k0 + (sc >> 1));
        }
        __syncthreads();
#pragma unroll
        for (int ks = 0; ks < 2; ++ks) {
            s16x8 aF[2], bF[4];
#pragma unroll
            for (int mi = 0; mi < 2; ++mi) {
                int row = wr * 32 + mi * 16 + lo16;
                int cb = ks * 64 + hi * 16;
                aF[mi] = *(const s16x8*)((const char*)As + row * 128 + (cb ^ ((row & 7) << 4)));
            }
#pragma unroll
            for (int ni = 0; ni < 4; ++ni) {
                int row = ni * 16 + lo16;
                int cb = ks * 64 + hi * 16;
                bF[ni] = *(const s16x8*)((const char*)Bs + row * 128 + (cb ^ ((row & 7) << 4)));
            }
#pragma unroll
            for (int mi = 0; mi < 2; ++mi)
#pragma unroll
                for (int ni = 0; ni < 4; ++ni)
                    acc[mi][ni] = MFMA(aF[mi], bF[ni], acc[mi][ni]);
        }
    }

    float bv4[4];
#pragma unroll
    for (int ni = 0; ni < 4; ++ni) bv4[ni] = bo[n0 + ni * 16 + lo16];
#pragma unroll
    for (int mi = 0; mi < 2; ++mi)
#pragma unroll
        for (int ni = 0; ni < 4; ++ni)
#pragma unroll
            for (int r = 0; r < 4; ++r) {
                int m = m0 + wr * 32 + mi * 16 + hi * 4 + r;
                out[(size_t)m * 1024 + n0 + ni * 16 + lo16] = acc[mi][ni][r] + bv4[ni];
            }
}

// ---------------------------------------------------------------------------
extern "C" void kernel_launch(void* const* d_in, const int* in_sizes, int n_in,
                              void* d_out, int out_size, void* d_ws, size_t ws_size,
                              hipStream_t stream)
{
    (void)in_sizes; (void)n_in; (void)out_size; (void)ws_size;
    const float* x    = (const float*)d_in[0];
    const float* mask = (const float*)d_in[1];
    const float* wq   = (const float*)d_in[2];
    const float* bq   = (const float*)d_in[3];
    const float* wk   = (const float*)d_in[4];
    const float* bk   = (const float*)d_in[5];
    const float* wv   = (const float*)d_in[6];
    const float* bv   = (const float*)d_in[7];
    const float* wo   = (const float*)d_in[8];
    const float* bo   = (const float*)d_in[9];
    const float* relk = (const float*)d_in[10];
    const float* relv = (const float*)d_in[11];
    float* out = (float*)d_out;

    char* p = (char*)d_ws;
    short* xb    = (short*)p; p += (size_t)4096 * 1024 * 2;     // 8 MB
    short* Wtqkv = (short*)p; p += (size_t)3072 * 1024 * 2;     // 6 MB
    short* Wto   = (short*)p; p += (size_t)1024 * 1024 * 2;     // 2 MB
    short* Qb    = (short*)p; p += (size_t)4096 * 1024 * 2;     // 8 MB
    short* Kb    = (short*)p; p += (size_t)4096 * 1024 * 2;     // 8 MB
    short* Vtb   = (short*)p; p += (size_t)4096 * 1024 * 2;     // 8 MB
    short* CTXb  = (short*)p; p += (size_t)4096 * 1024 * 2;     // 8 MB
    short* relkb = (short*)p; p += (size_t)144 * 64 * 2;
    short* relvT = (short*)p; p += (size_t)64 * 128 * 2;

    cast_x       <<<2048, 256, 0, stream>>>(x, xb);
    transpose_w  <<<dim3(16, 16, 4), 256, 0, stream>>>(wq, wk, wv, wo, Wtqkv, Wto);
    prep_tables  <<<1, 256, 0, stream>>>(relk, relv, relkb, relvT);
    gemm_qkv     <<<dim3(24, 32), 256, 0, stream>>>(xb, Wtqkv, bq, bk, bv, Qb, Kb, Vtb);
    attn_mfma    <<<1024, 256, 0, stream>>>(Qb, Kb, Vtb, relkb, relvT, relv, mask, CTXb);
    gemm_out     <<<dim3(16, 32), 256, 0, stream>>>(CTXb, Wto, bo, out);
}

// Round 7
// 160.147 us; speedup vs baseline: 1.7424x; 1.0932x over previous
//
#include <hip/hip_runtime.h>
#include <hip/hip_bf16.h>
#include <cstdint>
#include <cstddef>

typedef unsigned int u32;
typedef __attribute__((ext_vector_type(8))) short s16x8;   // 8 bf16 (4 VGPR) MFMA A/B frag
typedef __attribute__((ext_vector_type(4))) short s16x4;   // 4 bf16, 8B pack
typedef __attribute__((ext_vector_type(4))) float f32x4;   // MFMA C/D frag
typedef __attribute__((ext_vector_type(2))) u32   u32x2;

#define MFMA(a,b,c) __builtin_amdgcn_mfma_f32_16x16x32_bf16(a,b,c,0,0,0)

#if __has_builtin(__builtin_amdgcn_mfma_f32_16x16x16bf16_1k)
#define MFMA16(a,b,c) __builtin_amdgcn_mfma_f32_16x16x16bf16_1k(a,b,c,0,0,0)
#else
static __device__ __forceinline__ f32x4 MFMA16(s16x4 a, s16x4 b, f32x4 c){
    f32x4 d;
    asm("v_mfma_f32_16x16x16_bf16 %0, %1, %2, %3"
        : "=v"(d) : "v"(a), "v"(b), "v"(c));
    return d;
}
#endif

__device__ __forceinline__ short f2bf(float f) {
    u32 u = __builtin_bit_cast(u32, f);
    u32 r = (u + 0x7fffu + ((u >> 16) & 1u)) >> 16;   // RNE
    return (short)r;
}
__device__ __forceinline__ float bf2f(short s) {
    return __builtin_bit_cast(float, ((u32)(unsigned short)s) << 16);
}
__device__ __forceinline__ u32 cvtpk(float lo, float hi) {
    u32 r;
    asm("v_cvt_pk_bf16_f32 %0, %1, %2" : "=v"(r) : "v"(lo), "v"(hi));
    return r;
}
__device__ __forceinline__ void async_copy16(void* lds, const void* g) {
    __builtin_amdgcn_global_load_lds((const __attribute__((address_space(1))) u32*)g,
                                     (__attribute__((address_space(3))) u32*)lds, 16, 0, 0);
}

// ---------------------------------------------------------------------------
// Prep: cast x (fp32 -> bf16), 8 elems/thread
// ---------------------------------------------------------------------------
__global__ __launch_bounds__(256) void cast_x(const float* __restrict__ x, short* __restrict__ xb) {
    int i = (blockIdx.x * 256 + threadIdx.x) * 8;
    float4 a = *(const float4*)&x[i];
    float4 b = *(const float4*)&x[i + 4];
    s16x8 v = { f2bf(a.x), f2bf(a.y), f2bf(a.z), f2bf(a.w),
                f2bf(b.x), f2bf(b.y), f2bf(b.z), f2bf(b.w) };
    *(s16x8*)&xb[i] = v;
}

// ---------------------------------------------------------------------------
// Prep: transpose + cast weights. seg 0..2 -> Wtqkv rows [seg*1024, +1024); seg 3 -> Wto.
// ---------------------------------------------------------------------------
__global__ __launch_bounds__(256)
void transpose_w(const float* __restrict__ wq, const float* __restrict__ wk,
                 const float* __restrict__ wv, const float* __restrict__ wo,
                 short* __restrict__ Wtqkv, short* __restrict__ Wto)
{
    __shared__ float sT[64][68];
    const int kt = blockIdx.x, nt = blockIdx.y, seg = blockIdx.z;
    const float* src = seg == 0 ? wq : seg == 1 ? wk : seg == 2 ? wv : wo;
    const int k0 = kt * 64, n0 = nt * 64;
    const int tid = threadIdx.x;
#pragma unroll
    for (int i = 0; i < 4; ++i) {
        int t2 = tid + i * 256;          // 0..1023 -> 64 rows x 16 float4
        int r = t2 >> 4, c4 = t2 & 15;
        *(float4*)&sT[r][c4 * 4] = *(const float4*)&src[(size_t)(k0 + r) * 1024 + n0 + c4 * 4];
    }
    __syncthreads();
#pragma unroll
    for (int i = 0; i < 2; ++i) {
        int t2 = tid + i * 256;
        int rn = t2 >> 3, ch = t2 & 7;
        s16x8 v;
#pragma unroll
        for (int j = 0; j < 8; ++j) v[j] = f2bf(sT[ch * 8 + j][rn]);
        if (seg < 3)
            *(s16x8*)&Wtqkv[(size_t)(seg * 1024 + n0 + rn) * 1024 + k0 + ch * 8] = v;
        else
            *(s16x8*)&Wto[(size_t)(n0 + rn) * 1024 + k0 + ch * 8] = v;
    }
}

// ---------------------------------------------------------------------------
// Prep: relkb [144][64] bf16 zero-padded rows>=129; relvT [64][128] bf16 (r<128).
// ---------------------------------------------------------------------------
__global__ __launch_bounds__(256)
void prep_tables(const float* __restrict__ relk, const float* __restrict__ relv,
                 short* __restrict__ relkb, short* __restrict__ relvT)
{
    int tid = threadIdx.x;
    for (int i = tid; i < 144 * 64; i += 256) {
        int r = i >> 6, d = i & 63;
        relkb[i] = (r < 129) ? f2bf(relk[r * 64 + d]) : (short)0;
    }
    for (int i = tid; i < 64 * 128; i += 256) {
        int d = i >> 7, r = i & 127;
        relvT[i] = f2bf(relv[r * 64 + d]);
    }
}

// ---------------------------------------------------------------------------
// Fused QKV GEMM; V segment stores TRANSPOSED + k-interleaved:
// col(k) = (k>>5)*32 + (k&3) + (((k>>4)&1)<<2) + (((k>>2)&3)<<3)
// so attn's two 8B PV fragments (k=hi*4.., k=16+hi*4..) are one 16B chunk.
// ---------------------------------------------------------------------------
__global__ __launch_bounds__(256)
void gemm_qkv(const short* __restrict__ Ab, const short* __restrict__ Wt,
              const float* __restrict__ bq, const float* __restrict__ bk,
              const float* __restrict__ bv,
              short* __restrict__ Qb, short* __restrict__ Kb, short* __restrict__ Vtb)
{
    __shared__ __align__(16) short As[128 * 64];
    __shared__ __align__(16) short Bs[128 * 64];
    const int tid = threadIdx.x;
    const int w = tid >> 6, lane = tid & 63;
    const int lo16 = lane & 15, hi = lane >> 4;
    const int n0g = blockIdx.x * 128;
    const int m0 = blockIdx.y * 128;
    const int wr = w >> 1, wc = w & 1;

    f32x4 acc[4][4] = {};

    for (int t = 0; t < 16; ++t) {
        const int k0 = t * 64;
        __syncthreads();
#pragma unroll
        for (int i = 0; i < 4; ++i) {
            int o = i * 4096 + tid * 16;
            int row = o >> 7;
            int cb = o & 127;
            int sc = cb ^ ((row & 7) << 4);
            async_copy16((char*)As + o, Ab + (size_t)(m0 + row) * 1024 + k0 + (sc >> 1));
            async_copy16((char*)Bs + o, Wt + (size_t)(n0g + row) * 1024 + k0 + (sc >> 1));
        }
        __syncthreads();
#pragma unroll
        for (int ks = 0; ks < 2; ++ks) {
            s16x8 aF[4], bF[4];
#pragma unroll
            for (int mi = 0; mi < 4; ++mi) {
                int row = wr * 64 + mi * 16 + lo16;
                int cb = ks * 64 + hi * 16;
                aF[mi] = *(const s16x8*)((const char*)As + row * 128 + (cb ^ ((row & 7) << 4)));
            }
#pragma unroll
            for (int ni = 0; ni < 4; ++ni) {
                int row = wc * 64 + ni * 16 + lo16;
                int cb = ks * 64 + hi * 16;
                bF[ni] = *(const s16x8*)((const char*)Bs + row * 128 + (cb ^ ((row & 7) << 4)));
            }
#pragma unroll
            for (int mi = 0; mi < 4; ++mi)
#pragma unroll
                for (int ni = 0; ni < 4; ++ni)
                    acc[mi][ni] = MFMA(aF[mi], bF[ni], acc[mi][ni]);
        }
    }

    const int seg = n0g >> 10;
    const int nn = n0g & 1023;
    const float* bias = seg == 0 ? bq : seg == 1 ? bk : bv;
    float bv4[4];
#pragma unroll
    for (int ni = 0; ni < 4; ++ni) bv4[ni] = bias[nn + wc * 64 + ni * 16 + lo16];

    if (seg == 2) {
        // V: store transposed + interleaved, 4 consecutive l per thread -> 8B stores
#pragma unroll
        for (int mi = 0; mi < 4; ++mi)
#pragma unroll
            for (int ni = 0; ni < 4; ++ni) {
                int nl = nn + wc * 64 + ni * 16 + lo16;
                int hh = nl >> 6, d = nl & 63;
                int mbase = m0 + wr * 64 + mi * 16 + hi * 4;
                int bb = mbase >> 10, l0 = mbase & 1023;
                int j0 = l0 & 31;                          // j0 % 4 == 0
                int col = (l0 >> 5) * 32 + (((j0 >> 4) & 1) << 2) + (((j0 >> 2) & 3) << 3);
                s16x4 pk = { f2bf(acc[mi][ni][0] + bv4[ni]),
                             f2bf(acc[mi][ni][1] + bv4[ni]),
                             f2bf(acc[mi][ni][2] + bv4[ni]),
                             f2bf(acc[mi][ni][3] + bv4[ni]) };
                *(s16x4*)&Vtb[((size_t)(bb * 16 + hh) * 64 + d) * 1024 + col] = pk;
            }
    } else {
        short* out = seg == 0 ? Qb : Kb;
#pragma unroll
        for (int mi = 0; mi < 4; ++mi)
#pragma unroll
            for (int ni = 0; ni < 4; ++ni) {
                int nl = nn + wc * 64 + ni * 16 + lo16;
                int hh = nl >> 6, d = nl & 63;
#pragma unroll
                for (int r = 0; r < 4; ++r) {
                    int m = m0 + wr * 64 + mi * 16 + hi * 4 + r;
                    int bb = m >> 10, l = m & 1023;
                    out[(((size_t)bb * 16 + hh) * 1024 + l) * 64 + d] = f2bf(acc[mi][ni][r] + bv4[ni]);
                }
            }
    }
}

// ---------------------------------------------------------------------------
// Flash attention v5: LDS double-buffer + REGISTER PREFETCH one tile ahead
// (K/V/mask frags for tile t+1 read from LDS during tile t's compute).
// V stored k-interleaved -> 4x ds_read_b128, bank-uniform. QK un-chained.
// ---------------------------------------------------------------------------
struct TileRegs {
    s16x8 k0, k1, k2, k3;    // K frags (QK A-operand)
    s16x8 v0, v1, v2, v3;    // V frags (two 8B PV A-frags packed per 16B)
    s16x4 m0, m1;            // mask bias
};

__device__ __forceinline__ void prefetch_tile(
    const short* __restrict__ sKc, const short* __restrict__ sVc,
    const short* __restrict__ sMaskP, int kfm, int lo16, int hi, TileRegs& R)
{
    const int km = lo16 & 7;
    R.k0 = *(const s16x8*)(sKc + lo16 * 64 + ((hi ^ km) << 3));
    R.k1 = *(const s16x8*)(sKc + lo16 * 64 + (((hi + 4) ^ km) << 3));
    R.k2 = *(const s16x8*)(sKc + (lo16 + 16) * 64 + ((hi ^ km) << 3));
    R.k3 = *(const s16x8*)(sKc + (lo16 + 16) * 64 + (((hi + 4) ^ km) << 3));
    R.v0 = *(const s16x8*)(sVc + lo16 * 32 + hi * 8);
    R.v1 = *(const s16x8*)(sVc + (16 + lo16) * 32 + hi * 8);
    R.v2 = *(const s16x8*)(sVc + (32 + lo16) * 32 + hi * 8);
    R.v3 = *(const s16x8*)(sVc + (48 + lo16) * 32 + hi * 8);
    R.m0 = *(const s16x4*)&sMaskP[kfm + hi * 4];
    R.m1 = *(const s16x4*)&sMaskP[kfm + 16 + hi * 4];
}

__device__ __forceinline__ void process32(
    int kf, int q0, int q_abs, int lo16, int hi,
    const TileRegs& R,
    const s16x8& qB0, const s16x8& qB1,
    float qrel_lo, float qrel_hi,
    const short (*sQrelw)[148], short (*sBandw)[128],
    f32x4* ctx, float& lsum, float& lov, float& hiv)
{
    const f32x4 z = {0.f, 0.f, 0.f, 0.f};
    __builtin_amdgcn_s_setprio(1);
    f32x4 sa = MFMA(R.k0, qB0, z);
    f32x4 sb = MFMA(R.k1, qB1, z);
    f32x4 sc = MFMA(R.k2, qB0, z);
    f32x4 sd = MFMA(R.k3, qB1, z);
    __builtin_amdgcn_s_setprio(0);
    f32x4 s0 = sa + sb, s1 = sc + sd;

    float p[8];
    if (kf + 95 <= q0 || kf >= q0 + 79) {
        // whole block out of band: rel uniform 0 or 128
        const float qc = (kf < q0) ? qrel_lo : qrel_hi;
        float bs = 0.f;
#pragma unroll
        for (int r = 0; r < 4; ++r) {
            p[r]     = __expf(s0[r] + qc + bf2f(R.m0[r]));
            p[4 + r] = __expf(s1[r] + qc + bf2f(R.m1[r]));
        }
#pragma unroll
        for (int r = 0; r < 8; ++r) bs += p[r];
        lsum += bs;
        if (kf < q0) lov += bs; else hiv += bs;
    } else {
#pragma unroll
        for (int f = 0; f < 2; ++f)
#pragma unroll
            for (int r = 0; r < 4; ++r) {
                int k_abs = kf + f * 16 + hi * 4 + r;
                int dd = k_abs - q_abs;
                dd = dd < -64 ? -64 : (dd > 64 ? 64 : dd);
                int rel = dd + 64;
                float sv = f ? s1[r] : s0[r];
                float mv = bf2f(f ? R.m1[r] : R.m0[r]);
                float pex = __expf(sv + bf2f(sQrelw[lo16][rel]) + mv);
                p[f * 4 + r] = pex;
                lsum += pex;
                if (rel >= 1 && rel <= 127) sBandw[lo16][rel] = f2bf(pex);
                else if (rel == 0) lov += pex;
                else hiv += pex;
            }
    }

    // S-frag (col=q=lo16, k=hi*4+r) IS the 16x16x16 B-operand layout: no shuffle.
    u32x2 w0 = { cvtpk(p[0], p[1]), cvtpk(p[2], p[3]) };
    u32x2 w1 = { cvtpk(p[4], p[5]), cvtpk(p[6], p[7]) };
    s16x4 pf0 = __builtin_bit_cast(s16x4, w0);
    s16x4 pf1 = __builtin_bit_cast(s16x4, w1);

    // split interleaved V chunks: low 8B = f0 frag, high 8B = f1 frag
    s16x4 a0 = __builtin_shufflevector(R.v0, R.v0, 0, 1, 2, 3);
    s16x4 b0 = __builtin_shufflevector(R.v0, R.v0, 4, 5, 6, 7);
    s16x4 a1 = __builtin_shufflevector(R.v1, R.v1, 0, 1, 2, 3);
    s16x4 b1 = __builtin_shufflevector(R.v1, R.v1, 4, 5, 6, 7);
    s16x4 a2 = __builtin_shufflevector(R.v2, R.v2, 0, 1, 2, 3);
    s16x4 b2 = __builtin_shufflevector(R.v2, R.v2, 4, 5, 6, 7);
    s16x4 a3 = __builtin_shufflevector(R.v3, R.v3, 0, 1, 2, 3);
    s16x4 b3 = __builtin_shufflevector(R.v3, R.v3, 4, 5, 6, 7);

    __builtin_amdgcn_s_setprio(1);
    ctx[0] = MFMA16(a0, pf0, ctx[0]);
    ctx[1] = MFMA16(a1, pf0, ctx[1]);
    ctx[2] = MFMA16(a2, pf0, ctx[2]);
    ctx[3] = MFMA16(a3, pf0, ctx[3]);
    ctx[0] = MFMA16(b0, pf1, ctx[0]);
    ctx[1] = MFMA16(b1, pf1, ctx[1]);
    ctx[2] = MFMA16(b2, pf1, ctx[2]);
    ctx[3] = MFMA16(b3, pf1, ctx[3]);
    __builtin_amdgcn_s_setprio(0);
}

__global__ __launch_bounds__(256, 3)
void attn_mfma(const short* __restrict__ Qb, const short* __restrict__ Kb,
               const short* __restrict__ Vtb, const short* __restrict__ relkb,
               const short* __restrict__ relvTb, const float* __restrict__ relv_f32,
               const float* __restrict__ mask, short* __restrict__ CTXb)
{
    __shared__ __align__(16) short sK[2][32 * 64];     // 4KB/buf, XOR-swizzled chunks
    __shared__ __align__(16) short sV[2][64 * 32];     // 4KB/buf, k-interleaved, linear
    __shared__ __align__(16) short sMaskP[1024 + 32];  // bf16 mask * -1e9 (+pad for t=31 prefetch)
    __shared__ __align__(16) short sQrel[4][16][148];  // bf16 Qrel[q][r], r<=143
    __shared__ __align__(16) short sBand[4][16][128];  // bf16 band weights r in 1..127

    const int tid = threadIdx.x;
    const int w = tid >> 6, lane = tid & 63;
    const int lo16 = lane & 15, hi = lane >> 4;

    // XCD-aware swizzle (1024 = 8*128, bijective); same-bh blocks share an XCD L2
    const int p = blockIdx.x;
    const int bid = (p & 7) * 128 + (p >> 3);
    const int bh = bid >> 4;
    const int qt = bid & 15;
    const int b = bh >> 4, h = bh & 15;
    const int q0 = qt * 64 + w * 16;
    const int q_abs = q0 + lo16;

    const short* Kbase = Kb + (size_t)bh * 65536;
    const short* Vtbase = Vtb + (size_t)bh * 65536;

    // staging geometry (per thread, 1x16B for K + 1x16B for V per tile)
    const int skr = tid >> 3, skc = tid & 7;             // K: row 0..31, chunk 0..7
    const int svd = tid >> 2, svc = tid & 3;             // V: row d 0..63, chunk 0..3
    const short* ksrc = Kbase + (size_t)skr * 64 + ((skc ^ (skr & 7)) << 3);
    const short* vsrc = Vtbase + (size_t)svd * 1024 + svc * 8;   // linear (interleave is in global layout)

    // stage tiles 0 and 1
    async_copy16((char*)&sK[0][0] + tid * 16, ksrc);
    async_copy16((char*)&sV[0][0] + tid * 16, vsrc);
    async_copy16((char*)&sK[1][0] + tid * 16, ksrc + 32 * 64);
    async_copy16((char*)&sV[1][0] + tid * 16, vsrc + 32);

    // persistent Q fragments (B-operand: col = q = lane&15, depth = hi*8+j)
    const short* qptr = Qb + ((size_t)bh * 1024 + q_abs) * 64 + hi * 8;
    const s16x8 qB0 = *(const s16x8*)qptr;
    const s16x8 qB1 = *(const s16x8*)(qptr + 32);

    // init shared: maskP (block-wide), sBand zero (per-wave region)
    {
        float4 mv = *(const float4*)&mask[b * 1024 + tid * 4];
        s16x4 mp = { f2bf(mv.x * -1e9f), f2bf(mv.y * -1e9f),
                     f2bf(mv.z * -1e9f), f2bf(mv.w * -1e9f) };
        *(s16x4*)&sMaskP[tid * 4] = mp;
        if (tid < 8) *(s16x4*)&sMaskP[1024 + tid * 4] = s16x4{0, 0, 0, 0};
    }
    {
        u32* bz = (u32*)&sBand[w][0][0];   // 16*128 shorts = 1024 u32 per wave
#pragma unroll
        for (int i = 0; i < 16; ++i) bz[lane + i * 64] = 0u;
    }

    // Qrel^T = relk @ Q^T : 9 r-frags -> sQrel[w][q][r] (bf16)
#pragma unroll
    for (int rf = 0; rf < 9; ++rf) {
        const short* rp = relkb + (size_t)(rf * 16 + lo16) * 64 + hi * 8;
        s16x8 rA0 = *(const s16x8*)rp;
        s16x8 rA1 = *(const s16x8*)(rp + 32);
        f32x4 dq = {0.f, 0.f, 0.f, 0.f};
        dq = MFMA(rA0, qB0, dq);
        dq = MFMA(rA1, qB1, dq);
        s16x4 pk = { f2bf(dq[0]), f2bf(dq[1]), f2bf(dq[2]), f2bf(dq[3]) };
        *(s16x4*)&sQrel[w][lo16][rf * 16 + hi * 4] = pk;
    }
    __syncthreads();   // drains stage(0/1) vmcnt; fences sMaskP/sQrel

    const float qrel_lo = bf2f(sQrel[w][lo16][0]);
    const float qrel_hi = bf2f(sQrel[w][lo16][128]);

    f32x4 ctx[4] = {};
    float lsum = 0.f, lov = 0.f, hiv = 0.f;

    // load tile 0 frags into regs, and FENCE before any staging can overwrite buf0
    TileRegs C, N;
    prefetch_tile(sK[0], sV[0], sMaskP, 0, lo16, hi, C);
    asm volatile("s_waitcnt lgkmcnt(0)" ::: "memory");
    __builtin_amdgcn_sched_barrier(0);

    for (int t = 0; t < 32; ++t) {
        if (t < 30) {   // stage tile t+2 into buf[t&1] (its last reads ended at iter t-1's barrier)
            int kfn = (t + 2) * 32;
            async_copy16((char*)&sK[t & 1][0] + tid * 16, ksrc + (size_t)kfn * 64);
            async_copy16((char*)&sV[t & 1][0] + tid * 16, vsrc + kfn);
        }
        // prefetch tile t+1 frags (buffer valid since end of iter t-1)
        prefetch_tile(sK[(t + 1) & 1], sV[(t + 1) & 1], sMaskP,
                      ((t + 1) * 32) & 1023, lo16, hi, N);
        process32(t * 32, q0, q_abs, lo16, hi, C, qB0, qB1, qrel_lo, qrel_hi,
                  sQrel[w], sBand[w], ctx, lsum, lov, hiv);
        __syncthreads();   // drains staging vmcnt + all waves' LDS reads
        C = N;
    }

    // band rel_v contribution: ctx^T += relvT-frag x sBand-frag (unnormalized)
#pragma unroll
    for (int ks = 0; ks < 4; ++ks) {
        s16x8 bB = *(const s16x8*)&sBand[w][lo16][ks * 32 + hi * 8];
#pragma unroll
        for (int df = 0; df < 4; ++df) {
            s16x8 rA = *(const s16x8*)(relvTb + (size_t)(df * 16 + lo16) * 128 + ks * 32 + hi * 8);
            ctx[df] = MFMA(rA, bB, ctx[df]);
        }
    }

    // reduce per-q stats across the 4 hi-groups
    lsum += __shfl_xor(lsum, 16); lsum += __shfl_xor(lsum, 32);
    lov  += __shfl_xor(lov, 16);  lov  += __shfl_xor(lov, 32);
    hiv  += __shfl_xor(hiv, 16);  hiv  += __shfl_xor(hiv, 32);
    const float inv = 1.0f / lsum;

    // tails (clipped buckets 0 / 128) + normalize + store bf16 ctx
#pragma unroll
    for (int df = 0; df < 4; ++df) {
        s16x4 pk;
#pragma unroll
        for (int r = 0; r < 4; ++r) {
            int d = df * 16 + hi * 4 + r;
            float t = ctx[df][r] + lov * relv_f32[d] + hiv * relv_f32[128 * 64 + d];
            pk[r] = f2bf(t * inv);
        }
        *(s16x4*)(CTXb + ((size_t)(b * 1024) + q_abs) * 1024 + h * 64 + df * 16 + hi * 4) = pk;
    }
}

// ---------------------------------------------------------------------------
// Output GEMM: out[4096,1024] = CTXb @ wo + bo (fp32 out). 128x64 tile, BK=64.
// ---------------------------------------------------------------------------
__global__ __launch_bounds__(256)
void gemm_out(const short* __restrict__ Ab, const short* __restrict__ Wto,
              const float* __restrict__ bo, float* __restrict__ out)
{
    __shared__ __align__(16) short As[128 * 64];
    __shared__ __align__(16) short Bs[64 * 64];
    const int tid = threadIdx.x;
    const int w = tid >> 6, lane = tid & 63;
    const int lo16 = lane & 15, hi = lane >> 4;
    const int n0 = blockIdx.x * 64;
    const int m0 = blockIdx.y * 128;
    const int wr = w;

    f32x4 acc[2][4] = {};

    for (int t = 0; t < 16; ++t) {
        const int k0 = t * 64;
        __syncthreads();
#pragma unroll
        for (int i = 0; i < 4; ++i) {
            int o = i * 4096 + tid * 16;
            int row = o >> 7;
            int cb = o & 127;
            int sc = cb ^ ((row & 7) << 4);
            async_copy16((char*)As + o, Ab + (size_t)(m0 + row) * 1024 + k0 + (sc >> 1));
        }
#pragma unroll
        for (int i = 0; i < 2; ++i) {
            int o = i * 4096 + tid * 16;
            int row = o >> 7;
            int cb = o & 127;
            int sc = cb ^ ((row & 7) << 4);
            async_copy16((char*)Bs + o, Wto + (size_t)(n0 + row) * 1024 + k0 + (sc >> 1));
        }
        __syncthreads();
#pragma unroll
        for (int ks = 0; ks < 2; ++ks) {
            s16x8 aF[2], bF[4];
#pragma unroll
            for (int mi = 0; mi < 2; ++mi) {
                int row = wr * 32 + mi * 16 + lo16;
                int cb = ks * 64 + hi * 16;
                aF[mi] = *(const s16x8*)((const char*)As + row * 128 + (cb ^ ((row & 7) << 4)));
            }
#pragma unroll
            for (int ni = 0; ni < 4; ++ni) {
                int row = ni * 16 + lo16;
                int cb = ks * 64 + hi * 16;
                bF[ni] = *(const s16x8*)((const char*)Bs + row * 128 + (cb ^ ((row & 7) << 4)));
            }
#pragma unroll
            for (int mi = 0; mi < 2; ++mi)
#pragma unroll
                for (int ni = 0; ni < 4; ++ni)
                    acc[mi][ni] = MFMA(aF[mi], bF[ni], acc[mi][ni]);
        }
    }

    float bv4[4];
#pragma unroll
    for (int ni = 0; ni < 4; ++ni) bv4[ni] = bo[n0 + ni * 16 + lo16];
#pragma unroll
    for (int mi = 0; mi < 2; ++mi)
#pragma unroll
        for (int ni = 0; ni < 4; ++ni)
#pragma unroll
            for (int r = 0; r < 4; ++r) {
                int m = m0 + wr * 32 + mi * 16 + hi * 4 + r;
                out[(size_t)m * 1024 + n0 + ni * 16 + lo16] = acc[mi][ni][r] + bv4[ni];
            }
}

// ---------------------------------------------------------------------------
extern "C" void kernel_launch(void* const* d_in, const int* in_sizes, int n_in,
                              void* d_out, int out_size, void* d_ws, size_t ws_size,
                              hipStream_t stream)
{
    (void)in_sizes; (void)n_in; (void)out_size; (void)ws_size;
    const float* x    = (const float*)d_in[0];
    const float* mask = (const float*)d_in[1];
    const float* wq   = (const float*)d_in[2];
    const float* bq   = (const float*)d_in[3];
    const float* wk   = (const float*)d_in[4];
    const float* bk   = (const float*)d_in[5];
    const float* wv   = (const float*)d_in[6];
    const float* bv   = (const float*)d_in[7];
    const float* wo   = (const float*)d_in[8];
    const float* bo   = (const float*)d_in[9];
    const float* relk = (const float*)d_in[10];
    const float* relv = (const float*)d_in[11];
    float* out = (float*)d_out;

    char* p = (char*)d_ws;
    short* xb    = (short*)p; p += (size_t)4096 * 1024 * 2;     // 8 MB
    short* Wtqkv = (short*)p; p += (size_t)3072 * 1024 * 2;     // 6 MB
    short* Wto   = (short*)p; p += (size_t)1024 * 1024 * 2;     // 2 MB
    short* Qb    = (short*)p; p += (size_t)4096 * 1024 * 2;     // 8 MB
    short* Kb    = (short*)p; p += (size_t)4096 * 1024 * 2;     // 8 MB
    short* Vtb   = (short*)p; p += (size_t)4096 * 1024 * 2;     // 8 MB
    short* CTXb  = (short*)p; p += (size_t)4096 * 1024 * 2;     // 8 MB
    short* relkb = (short*)p; p += (size_t)144 * 64 * 2;
    short* relvT = (short*)p; p += (size_t)64 * 128 * 2;

    cast_x       <<<2048, 256, 0, stream>>>(x, xb);
    transpose_w  <<<dim3(16, 16, 4), 256, 0, stream>>>(wq, wk, wv, wo, Wtqkv, Wto);
    prep_tables  <<<1, 256, 0, stream>>>(relk, relv, relkb, relvT);
    gemm_qkv     <<<dim3(24, 32), 256, 0, stream>>>(xb, Wtqkv, bq, bk, bv, Qb, Kb, Vtb);
    attn_mfma    <<<1024, 256, 0, stream>>>(Qb, Kb, Vtb, relkb, relvT, relv, mask, CTXb);
    gemm_out     <<<dim3(16, 32), 256, 0, stream>>>(CTXb, Wto, bo, out);
}

// Round 10
// 154.086 us; speedup vs baseline: 1.8109x; 1.0393x over previous
//
#include <hip/hip_runtime.h>
#include <hip/hip_bf16.h>
#include <cstdint>
#include <cstddef>

typedef unsigned int u32;
typedef __attribute__((ext_vector_type(8))) short s16x8;   // 8 bf16 (4 VGPR) MFMA A/B frag
typedef __attribute__((ext_vector_type(4))) short s16x4;   // 4 bf16, 8B pack
typedef __attribute__((ext_vector_type(4))) float f32x4;   // MFMA C/D frag
typedef __attribute__((ext_vector_type(2))) u32   u32x2;

#define MFMA(a,b,c) __builtin_amdgcn_mfma_f32_16x16x32_bf16(a,b,c,0,0,0)

#if __has_builtin(__builtin_amdgcn_mfma_f32_16x16x16bf16_1k)
#define MFMA16(a,b,c) __builtin_amdgcn_mfma_f32_16x16x16bf16_1k(a,b,c,0,0,0)
#else
static __device__ __forceinline__ f32x4 MFMA16(s16x4 a, s16x4 b, f32x4 c){
    f32x4 d;
    asm("v_mfma_f32_16x16x16_bf16 %0, %1, %2, %3"
        : "=v"(d) : "v"(a), "v"(b), "v"(c));
    return d;
}
#endif

__device__ __forceinline__ short f2bf(float f) {
    u32 u = __builtin_bit_cast(u32, f);
    u32 r = (u + 0x7fffu + ((u >> 16) & 1u)) >> 16;   // RNE
    return (short)r;
}
__device__ __forceinline__ float bf2f(short s) {
    return __builtin_bit_cast(float, ((u32)(unsigned short)s) << 16);
}
__device__ __forceinline__ u32 cvtpk(float lo, float hi) {
    u32 r;
    asm("v_cvt_pk_bf16_f32 %0, %1, %2" : "=v"(r) : "v"(lo), "v"(hi));
    return r;
}
__device__ __forceinline__ void async_copy16(void* lds, const void* g) {
    __builtin_amdgcn_global_load_lds((const __attribute__((address_space(1))) u32*)g,
                                     (__attribute__((address_space(3))) u32*)lds, 16, 0, 0);
}

// ---------------------------------------------------------------------------
// Prep: cast x (fp32 -> bf16), 8 elems/thread
// ---------------------------------------------------------------------------
__global__ __launch_bounds__(256) void cast_x(const float* __restrict__ x, short* __restrict__ xb) {
    int i = (blockIdx.x * 256 + threadIdx.x) * 8;
    float4 a = *(const float4*)&x[i];
    float4 b = *(const float4*)&x[i + 4];
    s16x8 v = { f2bf(a.x), f2bf(a.y), f2bf(a.z), f2bf(a.w),
                f2bf(b.x), f2bf(b.y), f2bf(b.z), f2bf(b.w) };
    *(s16x8*)&xb[i] = v;
}

// ---------------------------------------------------------------------------
// Prep: transpose + cast weights. seg 0..2 -> Wtqkv rows [seg*1024, +1024); seg 3 -> Wto.
// ---------------------------------------------------------------------------
__global__ __launch_bounds__(256)
void transpose_w(const float* __restrict__ wq, const float* __restrict__ wk,
                 const float* __restrict__ wv, const float* __restrict__ wo,
                 short* __restrict__ Wtqkv, short* __restrict__ Wto)
{
    __shared__ float sT[64][68];
    const int kt = blockIdx.x, nt = blockIdx.y, seg = blockIdx.z;
    const float* src = seg == 0 ? wq : seg == 1 ? wk : seg == 2 ? wv : wo;
    const int k0 = kt * 64, n0 = nt * 64;
    const int tid = threadIdx.x;
#pragma unroll
    for (int i = 0; i < 4; ++i) {
        int t2 = tid + i * 256;          // 0..1023 -> 64 rows x 16 float4
        int r = t2 >> 4, c4 = t2 & 15;
        *(float4*)&sT[r][c4 * 4] = *(const float4*)&src[(size_t)(k0 + r) * 1024 + n0 + c4 * 4];
    }
    __syncthreads();
#pragma unroll
    for (int i = 0; i < 2; ++i) {
        int t2 = tid + i * 256;
        int rn = t2 >> 3, ch = t2 & 7;
        s16x8 v;
#pragma unroll
        for (int j = 0; j < 8; ++j) v[j] = f2bf(sT[ch * 8 + j][rn]);
        if (seg < 3)
            *(s16x8*)&Wtqkv[(size_t)(seg * 1024 + n0 + rn) * 1024 + k0 + ch * 8] = v;
        else
            *(s16x8*)&Wto[(size_t)(n0 + rn) * 1024 + k0 + ch * 8] = v;
    }
}

// ---------------------------------------------------------------------------
// Prep: relkb [144][64] bf16 zero-padded rows>=129; relvT [64][128] bf16 (r<128).
// ---------------------------------------------------------------------------
__global__ __launch_bounds__(256)
void prep_tables(const float* __restrict__ relk, const float* __restrict__ relv,
                 short* __restrict__ relkb, short* __restrict__ relvT)
{
    int tid = threadIdx.x;
    for (int i = tid; i < 144 * 64; i += 256) {
        int r = i >> 6, d = i & 63;
        relkb[i] = (r < 129) ? f2bf(relk[r * 64 + d]) : (short)0;
    }
    for (int i = tid; i < 64 * 128; i += 256) {
        int d = i >> 7, r = i & 127;
        relvT[i] = f2bf(relv[r * 64 + d]);
    }
}

// ---------------------------------------------------------------------------
// Fused QKV GEMM; V segment stores TRANSPOSED + k-interleaved:
// col(k) = (k>>5)*32 + (k&3) + (((k>>4)&1)<<2) + (((k>>2)&3)<<3)
// ---------------------------------------------------------------------------
__global__ __launch_bounds__(256)
void gemm_qkv(const short* __restrict__ Ab, const short* __restrict__ Wt,
              const float* __restrict__ bq, const float* __restrict__ bk,
              const float* __restrict__ bv,
              short* __restrict__ Qb, short* __restrict__ Kb, short* __restrict__ Vtb)
{
    __shared__ __align__(16) short As[128 * 64];
    __shared__ __align__(16) short Bs[128 * 64];
    const int tid = threadIdx.x;
    const int w = tid >> 6, lane = tid & 63;
    const int lo16 = lane & 15, hi = lane >> 4;
    const int n0g = blockIdx.x * 128;
    const int m0 = blockIdx.y * 128;
    const int wr = w >> 1, wc = w & 1;

    f32x4 acc[4][4] = {};

    for (int t = 0; t < 16; ++t) {
        const int k0 = t * 64;
        __syncthreads();
#pragma unroll
        for (int i = 0; i < 4; ++i) {
            int o = i * 4096 + tid * 16;
            int row = o >> 7;
            int cb = o & 127;
            int sc = cb ^ ((row & 7) << 4);
            async_copy16((char*)As + o, Ab + (size_t)(m0 + row) * 1024 + k0 + (sc >> 1));
            async_copy16((char*)Bs + o, Wt + (size_t)(n0g + row) * 1024 + k0 + (sc >> 1));
        }
        __syncthreads();
#pragma unroll
        for (int ks = 0; ks < 2; ++ks) {
            s16x8 aF[4], bF[4];
#pragma unroll
            for (int mi = 0; mi < 4; ++mi) {
                int row = wr * 64 + mi * 16 + lo16;
                int cb = ks * 64 + hi * 16;
                aF[mi] = *(const s16x8*)((const char*)As + row * 128 + (cb ^ ((row & 7) << 4)));
            }
#pragma unroll
            for (int ni = 0; ni < 4; ++ni) {
                int row = wc * 64 + ni * 16 + lo16;
                int cb = ks * 64 + hi * 16;
                bF[ni] = *(const s16x8*)((const char*)Bs + row * 128 + (cb ^ ((row & 7) << 4)));
            }
#pragma unroll
            for (int mi = 0; mi < 4; ++mi)
#pragma unroll
                for (int ni = 0; ni < 4; ++ni)
                    acc[mi][ni] = MFMA(aF[mi], bF[ni], acc[mi][ni]);
        }
    }

    const int seg = n0g >> 10;
    const int nn = n0g & 1023;
    const float* bias = seg == 0 ? bq : seg == 1 ? bk : bv;
    float bv4[4];
#pragma unroll
    for (int ni = 0; ni < 4; ++ni) bv4[ni] = bias[nn + wc * 64 + ni * 16 + lo16];

    if (seg == 2) {
        // V: store transposed + interleaved, 4 consecutive l per thread -> 8B stores
#pragma unroll
        for (int mi = 0; mi < 4; ++mi)
#pragma unroll
            for (int ni = 0; ni < 4; ++ni) {
                int nl = nn + wc * 64 + ni * 16 + lo16;
                int hh = nl >> 6, d = nl & 63;
                int mbase = m0 + wr * 64 + mi * 16 + hi * 4;
                int bb = mbase >> 10, l0 = mbase & 1023;
                int j0 = l0 & 31;                          // j0 % 4 == 0
                int col = (l0 >> 5) * 32 + (((j0 >> 4) & 1) << 2) + (((j0 >> 2) & 3) << 3);
                s16x4 pk = { f2bf(acc[mi][ni][0] + bv4[ni]),
                             f2bf(acc[mi][ni][1] + bv4[ni]),
                             f2bf(acc[mi][ni][2] + bv4[ni]),
                             f2bf(acc[mi][ni][3] + bv4[ni]) };
                *(s16x4*)&Vtb[((size_t)(bb * 16 + hh) * 64 + d) * 1024 + col] = pk;
            }
    } else {
        short* out = seg == 0 ? Qb : Kb;
#pragma unroll
        for (int mi = 0; mi < 4; ++mi)
#pragma unroll
            for (int ni = 0; ni < 4; ++ni) {
                int nl = nn + wc * 64 + ni * 16 + lo16;
                int hh = nl >> 6, d = nl & 63;
#pragma unroll
                for (int r = 0; r < 4; ++r) {
                    int m = m0 + wr * 64 + mi * 16 + hi * 4 + r;
                    int bb = m >> 10, l = m & 1023;
                    out[(((size_t)bb * 16 + hh) * 1024 + l) * 64 + d] = f2bf(acc[mi][ni][r] + bv4[ni]);
                }
            }
    }
}

// ---------------------------------------------------------------------------
// Flash attention v7: round-7 sync semantics (__syncthreads only, proven),
// but 64-k tiles per barrier: two 32-k sub-chunks processed per drain.
// Register prefetch: sub1 during sub0's compute, next-tile sub0 right after
// the barrier. 4x global_load_lds staging per tile.
// ---------------------------------------------------------------------------
struct TileRegs {
    s16x8 k0, k1, k2, k3;    // K frags (QK A-operand)
    s16x8 v0, v1, v2, v3;    // V frags (two 8B PV A-frags packed per 16B)
    s16x4 m0, m1;            // mask bias
};

__device__ __forceinline__ void prefetch_tile(
    const short* __restrict__ sKc, const short* __restrict__ sVc,
    const short* __restrict__ sMaskP, int kfm, int lo16, int hi, TileRegs& R)
{
    const int km = lo16 & 7;
    R.k0 = *(const s16x8*)(sKc + lo16 * 64 + ((hi ^ km) << 3));
    R.k1 = *(const s16x8*)(sKc + lo16 * 64 + (((hi + 4) ^ km) << 3));
    R.k2 = *(const s16x8*)(sKc + (lo16 + 16) * 64 + ((hi ^ km) << 3));
    R.k3 = *(const s16x8*)(sKc + (lo16 + 16) * 64 + (((hi + 4) ^ km) << 3));
    R.v0 = *(const s16x8*)(sVc + lo16 * 32 + hi * 8);
    R.v1 = *(const s16x8*)(sVc + (16 + lo16) * 32 + hi * 8);
    R.v2 = *(const s16x8*)(sVc + (32 + lo16) * 32 + hi * 8);
    R.v3 = *(const s16x8*)(sVc + (48 + lo16) * 32 + hi * 8);
    R.m0 = *(const s16x4*)&sMaskP[kfm + hi * 4];
    R.m1 = *(const s16x4*)&sMaskP[kfm + 16 + hi * 4];
}

__device__ __forceinline__ void process32(
    int kf, int q0, int q_abs, int lo16, int hi,
    const TileRegs& R,
    const s16x8& qB0, const s16x8& qB1,
    float qrel_lo, float qrel_hi,
    const short (*sQrelw)[148], short (*sBandw)[128],
    f32x4* ctx, float& lsum, float& lov, float& hiv)
{
    const f32x4 z = {0.f, 0.f, 0.f, 0.f};
    __builtin_amdgcn_s_setprio(1);
    f32x4 sa = MFMA(R.k0, qB0, z);
    f32x4 sb = MFMA(R.k1, qB1, z);
    f32x4 sc = MFMA(R.k2, qB0, z);
    f32x4 sd = MFMA(R.k3, qB1, z);
    __builtin_amdgcn_s_setprio(0);
    f32x4 s0 = sa + sb, s1 = sc + sd;

    float p[8];
    if (kf + 95 <= q0 || kf >= q0 + 79) {
        // whole block out of band: rel uniform 0 or 128
        const float qc = (kf < q0) ? qrel_lo : qrel_hi;
        float bs = 0.f;
#pragma unroll
        for (int r = 0; r < 4; ++r) {
            p[r]     = __expf(s0[r] + qc + bf2f(R.m0[r]));
            p[4 + r] = __expf(s1[r] + qc + bf2f(R.m1[r]));
        }
#pragma unroll
        for (int r = 0; r < 8; ++r) bs += p[r];
        lsum += bs;
        if (kf < q0) lov += bs; else hiv += bs;
    } else {
#pragma unroll
        for (int f = 0; f < 2; ++f)
#pragma unroll
            for (int r = 0; r < 4; ++r) {
                int k_abs = kf + f * 16 + hi * 4 + r;
                int dd = k_abs - q_abs;
                dd = dd < -64 ? -64 : (dd > 64 ? 64 : dd);
                int rel = dd + 64;
                float sv = f ? s1[r] : s0[r];
                float mv = bf2f(f ? R.m1[r] : R.m0[r]);
                float pex = __expf(sv + bf2f(sQrelw[lo16][rel]) + mv);
                p[f * 4 + r] = pex;
                lsum += pex;
                if (rel >= 1 && rel <= 127) sBandw[lo16][rel] = f2bf(pex);
                else if (rel == 0) lov += pex;
                else hiv += pex;
            }
    }

    // S-frag (col=q=lo16, k=hi*4+r) IS the 16x16x16 B-operand layout: no shuffle.
    u32x2 w0 = { cvtpk(p[0], p[1]), cvtpk(p[2], p[3]) };
    u32x2 w1 = { cvtpk(p[4], p[5]), cvtpk(p[6], p[7]) };
    s16x4 pf0 = __builtin_bit_cast(s16x4, w0);
    s16x4 pf1 = __builtin_bit_cast(s16x4, w1);

    // split interleaved V chunks: low 8B = f0 frag, high 8B = f1 frag
    s16x4 a0 = __builtin_shufflevector(R.v0, R.v0, 0, 1, 2, 3);
    s16x4 b0 = __builtin_shufflevector(R.v0, R.v0, 4, 5, 6, 7);
    s16x4 a1 = __builtin_shufflevector(R.v1, R.v1, 0, 1, 2, 3);
    s16x4 b1 = __builtin_shufflevector(R.v1, R.v1, 4, 5, 6, 7);
    s16x4 a2 = __builtin_shufflevector(R.v2, R.v2, 0, 1, 2, 3);
    s16x4 b2 = __builtin_shufflevector(R.v2, R.v2, 4, 5, 6, 7);
    s16x4 a3 = __builtin_shufflevector(R.v3, R.v3, 0, 1, 2, 3);
    s16x4 b3 = __builtin_shufflevector(R.v3, R.v3, 4, 5, 6, 7);

    __builtin_amdgcn_s_setprio(1);
    ctx[0] = MFMA16(a0, pf0, ctx[0]);
    ctx[1] = MFMA16(a1, pf0, ctx[1]);
    ctx[2] = MFMA16(a2, pf0, ctx[2]);
    ctx[3] = MFMA16(a3, pf0, ctx[3]);
    ctx[0] = MFMA16(b0, pf1, ctx[0]);
    ctx[1] = MFMA16(b1, pf1, ctx[1]);
    ctx[2] = MFMA16(b2, pf1, ctx[2]);
    ctx[3] = MFMA16(b3, pf1, ctx[3]);
    __builtin_amdgcn_s_setprio(0);
}

__global__ __launch_bounds__(256, 2)
void attn_mfma(const short* __restrict__ Qb, const short* __restrict__ Kb,
               const short* __restrict__ Vtb, const short* __restrict__ relkb,
               const short* __restrict__ relvTb, const float* __restrict__ relv_f32,
               const float* __restrict__ mask, short* __restrict__ CTXb)
{
    __shared__ __align__(16) short sK[2][2][32 * 64];  // [buf][sub], XOR-swizzled chunks
    __shared__ __align__(16) short sV[2][2][64 * 32];  // [buf][sub], k-interleaved
    __shared__ __align__(16) short sMaskP[1024 + 32];  // bf16 mask * -1e9
    __shared__ __align__(16) short sQrel[4][16][148];  // bf16 Qrel[q][r], r<=143
    __shared__ __align__(16) short sBand[4][16][128];  // bf16 band weights r in 1..127

    const int tid = threadIdx.x;
    const int w = tid >> 6, lane = tid & 63;
    const int lo16 = lane & 15, hi = lane >> 4;

    // XCD-aware swizzle (1024 = 8*128, bijective); same-bh blocks share an XCD L2
    const int p = blockIdx.x;
    const int bid = (p & 7) * 128 + (p >> 3);
    const int bh = bid >> 4;
    const int qt = bid & 15;
    const int b = bh >> 4, h = bh & 15;
    const int q0 = qt * 64 + w * 16;
    const int q_abs = q0 + lo16;

    const short* Kbase = Kb + (size_t)bh * 65536;
    const short* Vtbase = Vtb + (size_t)bh * 65536;

    // staging geometry (per thread, 1x16B per async op)
    const int skr = tid >> 3, skc = tid & 7;             // K: row 0..31, chunk 0..7
    const int svd = tid >> 2, svc = tid & 3;             // V: row d 0..63, chunk 0..3
    const short* ksrc = Kbase + (size_t)skr * 64 + ((skc ^ (skr & 7)) << 3);
    const short* vsrc = Vtbase + (size_t)svd * 1024 + svc * 8;   // interleave is in global layout

    // stage tile 0 (both 32-k subs) into buf 0
    async_copy16((char*)&sK[0][0][0] + tid * 16, ksrc);
    async_copy16((char*)&sK[0][1][0] + tid * 16, ksrc + 32 * 64);
    async_copy16((char*)&sV[0][0][0] + tid * 16, vsrc);
    async_copy16((char*)&sV[0][1][0] + tid * 16, vsrc + 32);

    // persistent Q fragments (B-operand: col = q = lane&15, depth = hi*8+j)
    const short* qptr = Qb + ((size_t)bh * 1024 + q_abs) * 64 + hi * 8;
    const s16x8 qB0 = *(const s16x8*)qptr;
    const s16x8 qB1 = *(const s16x8*)(qptr + 32);

    // init shared: maskP (block-wide), sBand zero (per-wave region)
    {
        float4 mv = *(const float4*)&mask[b * 1024 + tid * 4];
        s16x4 mp = { f2bf(mv.x * -1e9f), f2bf(mv.y * -1e9f),
                     f2bf(mv.z * -1e9f), f2bf(mv.w * -1e9f) };
        *(s16x4*)&sMaskP[tid * 4] = mp;
        if (tid < 8) *(s16x4*)&sMaskP[1024 + tid * 4] = s16x4{0, 0, 0, 0};
    }
    {
        u32* bz = (u32*)&sBand[w][0][0];   // 16*128 shorts = 1024 u32 per wave
#pragma unroll
        for (int i = 0; i < 16; ++i) bz[lane + i * 64] = 0u;
    }

    // Qrel^T = relk @ Q^T : 9 r-frags -> sQrel[w][q][r] (bf16)
#pragma unroll
    for (int rf = 0; rf < 9; ++rf) {
        const short* rp = relkb + (size_t)(rf * 16 + lo16) * 64 + hi * 8;
        s16x8 rA0 = *(const s16x8*)rp;
        s16x8 rA1 = *(const s16x8*)(rp + 32);
        f32x4 dq = {0.f, 0.f, 0.f, 0.f};
        dq = MFMA(rA0, qB0, dq);
        dq = MFMA(rA1, qB1, dq);
        s16x4 pk = { f2bf(dq[0]), f2bf(dq[1]), f2bf(dq[2]), f2bf(dq[3]) };
        *(s16x4*)&sQrel[w][lo16][rf * 16 + hi * 4] = pk;
    }
    __syncthreads();   // drains tile-0 staging; fences sMaskP/sQrel

    const float qrel_lo = bf2f(sQrel[w][lo16][0]);
    const float qrel_hi = bf2f(sQrel[w][lo16][128]);

    f32x4 ctx[4] = {};
    float lsum = 0.f, lov = 0.f, hiv = 0.f;

    // register-prefetch tile 0 / sub 0 (buf 0 valid; nobody overwrites buf 0
    // until iter 1's staging, which is after iter 0's __syncthreads)
    TileRegs C, N1;
    prefetch_tile(sK[0][0], sV[0][0], sMaskP, 0, lo16, hi, C);

    for (int t = 0; t < 16; ++t) {
        const int cb = t & 1, nb = (t + 1) & 1;
        const int kb = ((t + 1) & 15) * 64;    // wrapped next-tile base (t=15 -> 0, dead data)
        // stage tile t+1 (both subs) into buf nb
        async_copy16((char*)&sK[nb][0][0] + tid * 16, ksrc + (size_t)kb * 64);
        async_copy16((char*)&sK[nb][1][0] + tid * 16, ksrc + (size_t)(kb + 32) * 64);
        async_copy16((char*)&sV[nb][0][0] + tid * 16, vsrc + kb);
        async_copy16((char*)&sV[nb][1][0] + tid * 16, vsrc + kb + 32);
        // prefetch sub1 of current tile (staged last iter, drained by last barrier)
        prefetch_tile(sK[cb][1], sV[cb][1], sMaskP, t * 64 + 32, lo16, hi, N1);
        process32(t * 64,      q0, q_abs, lo16, hi, C,  qB0, qB1, qrel_lo, qrel_hi,
                  sQrel[w], sBand[w], ctx, lsum, lov, hiv);
        process32(t * 64 + 32, q0, q_abs, lo16, hi, N1, qB0, qB1, qrel_lo, qrel_hi,
                  sQrel[w], sBand[w], ctx, lsum, lov, hiv);
        __syncthreads();   // drains this iter's staging (vmcnt 0) + all waves' LDS reads
        // prefetch sub0 of tile t+1 (now fully staged and fenced)
        prefetch_tile(sK[nb][0], sV[nb][0], sMaskP, kb, lo16, hi, C);
    }

    // band rel_v contribution: ctx^T += relvT-frag x sBand-frag (unnormalized)
#pragma unroll
    for (int ks = 0; ks < 4; ++ks) {
        s16x8 bB = *(const s16x8*)&sBand[w][lo16][ks * 32 + hi * 8];
#pragma unroll
        for (int df = 0; df < 4; ++df) {
            s16x8 rA = *(const s16x8*)(relvTb + (size_t)(df * 16 + lo16) * 128 + ks * 32 + hi * 8);
            ctx[df] = MFMA(rA, bB, ctx[df]);
        }
    }

    // reduce per-q stats across the 4 hi-groups
    lsum += __shfl_xor(lsum, 16); lsum += __shfl_xor(lsum, 32);
    lov  += __shfl_xor(lov, 16);  lov  += __shfl_xor(lov, 32);
    hiv  += __shfl_xor(hiv, 16);  hiv  += __shfl_xor(hiv, 32);
    const float inv = 1.0f / lsum;

    // tails (clipped buckets 0 / 128) + normalize + store bf16 ctx
#pragma unroll
    for (int df = 0; df < 4; ++df) {
        s16x4 pk;
#pragma unroll
        for (int r = 0; r < 4; ++r) {
            int d = df * 16 + hi * 4 + r;
            float t = ctx[df][r] + lov * relv_f32[d] + hiv * relv_f32[128 * 64 + d];
            pk[r] = f2bf(t * inv);
        }
        *(s16x4*)(CTXb + ((size_t)(b * 1024) + q_abs) * 1024 + h * 64 + df * 16 + hi * 4) = pk;
    }
}

// ---------------------------------------------------------------------------
// Output GEMM: out[4096,1024] = CTXb @ wo + bo (fp32 out). 128x64 tile, BK=64.
// ---------------------------------------------------------------------------
__global__ __launch_bounds__(256)
void gemm_out(const short* __restrict__ Ab, const short* __restrict__ Wto,
              const float* __restrict__ bo, float* __restrict__ out)
{
    __shared__ __align__(16) short As[128 * 64];
    __shared__ __align__(16) short Bs[64 * 64];
    const int tid = threadIdx.x;
    const int w = tid >> 6, lane = tid & 63;
    const int lo16 = lane & 15, hi = lane >> 4;
    const int n0 = blockIdx.x * 64;
    const int m0 = blockIdx.y * 128;
    const int wr = w;

    f32x4 acc[2][4] = {};

    for (int t = 0; t < 16; ++t) {
        const int k0 = t * 64;
        __syncthreads();
#pragma unroll
        for (int i = 0; i < 4; ++i) {
            int o = i * 4096 + tid * 16;
            int row = o >> 7;
            int cb = o & 127;
            int sc = cb ^ ((row & 7) << 4);
            async_copy16((char*)As + o, Ab + (size_t)(m0 + row) * 1024 + k0 + (sc >> 1));
        }
#pragma unroll
        for (int i = 0; i < 2; ++i) {
            int o = i * 4096 + tid * 16;
            int row = o >> 7;
            int cb = o & 127;
            int sc = cb ^ ((row & 7) << 4);
            async_copy16((char*)Bs + o, Wto + (size_t)(n0 + row) * 1024 + k0 + (sc >> 1));
        }
        __syncthreads();
#pragma unroll
        for (int ks = 0; ks < 2; ++ks) {
            s16x8 aF[2], bF[4];
#pragma unroll
            for (int mi = 0; mi < 2; ++mi) {
                int row = wr * 32 + mi * 16 + lo16;
                int cb = ks * 64 + hi * 16;
                aF[mi] = *(const s16x8*)((const char*)As + row * 128 + (cb ^ ((row & 7) << 4)));
            }
#pragma unroll
            for (int ni = 0; ni < 4; ++ni) {
                int row = ni * 16 + lo16;
                int cb = ks * 64 + hi * 16;
                bF[ni] = *(const s16x8*)((const char*)Bs + row * 128 + (cb ^ ((row & 7) << 4)));
            }
#pragma unroll
            for (int mi = 0; mi < 2; ++mi)
#pragma unroll
                for (int ni = 0; ni < 4; ++ni)
                    acc[mi][ni] = MFMA(aF[mi], bF[ni], acc[mi][ni]);
        }
    }

    float bv4[4];
#pragma unroll
    for (int ni = 0; ni < 4; ++ni) bv4[ni] = bo[n0 + ni * 16 + lo16];
#pragma unroll
    for (int mi = 0; mi < 2; ++mi)
#pragma unroll
        for (int ni = 0; ni < 4; ++ni)
#pragma unroll
            for (int r = 0; r < 4; ++r) {
                int m = m0 + wr * 32 + mi * 16 + hi * 4 + r;
                out[(size_t)m * 1024 + n0 + ni * 16 + lo16] = acc[mi][ni][r] + bv4[ni];
            }
}

// ---------------------------------------------------------------------------
extern "C" void kernel_launch(void* const* d_in, const int* in_sizes, int n_in,
                              void* d_out, int out_size, void* d_ws, size_t ws_size,
                              hipStream_t stream)
{
    (void)in_sizes; (void)n_in; (void)out_size; (void)ws_size;
    const float* x    = (const float*)d_in[0];
    const float* mask = (const float*)d_in[1];
    const float* wq   = (const float*)d_in[2];
    const float* bq   = (const float*)d_in[3];
    const float* wk   = (const float*)d_in[4];
    const float* bk   = (const float*)d_in[5];
    const float* wv   = (const float*)d_in[6];
    const float* bv   = (const float*)d_in[7];
    const float* wo   = (const float*)d_in[8];
    const float* bo   = (const float*)d_in[9];
    const float* relk = (const float*)d_in[10];
    const float* relv = (const float*)d_in[11];
    float* out = (float*)d_out;

    char* p = (char*)d_ws;
    short* xb    = (short*)p; p += (size_t)4096 * 1024 * 2;     // 8 MB
    short* Wtqkv = (short*)p; p += (size_t)3072 * 1024 * 2;     // 6 MB
    short* Wto   = (short*)p; p += (size_t)1024 * 1024 * 2;     // 2 MB
    short* Qb    = (short*)p; p += (size_t)4096 * 1024 * 2;     // 8 MB
    short* Kb    = (short*)p; p += (size_t)4096 * 1024 * 2;     // 8 MB
    short* Vtb   = (short*)p; p += (size_t)4096 * 1024 * 2;     // 8 MB
    short* CTXb  = (short*)p; p += (size_t)4096 * 1024 * 2;     // 8 MB
    short* relkb = (short*)p; p += (size_t)144 * 64 * 2;
    short* relvT = (short*)p; p += (size_t)64 * 128 * 2;

    cast_x       <<<2048, 256, 0, stream>>>(x, xb);
    transpose_w  <<<dim3(16, 16, 4), 256, 0, stream>>>(wq, wk, wv, wo, Wtqkv, Wto);
    prep_tables  <<<1, 256, 0, stream>>>(relk, relv, relkb, relvT);
    gemm_qkv     <<<dim3(24, 32), 256, 0, stream>>>(xb, Wtqkv, bq, bk, bv, Qb, Kb, Vtb);
    attn_mfma    <<<1024, 256, 0, stream>>>(Qb, Kb, Vtb, relkb, relvT, relv, mask, CTXb);
    gemm_out     <<<dim3(16, 32), 256, 0, stream>>>(CTXb, Wto, bo, out);
}